// Round 21
// baseline (215.586 us; speedup 1.0000x reference)
//
#include <hip/hip_runtime.h>
#include <hip/hip_bf16.h>
#include <cstdint>

#define DEV __device__ __forceinline__

typedef __attribute__((ext_vector_type(8))) __bf16 bf16x8;
typedef __attribute__((ext_vector_type(4))) float f32x4;

// fp32 -> bf16 via HW cvt (single v_cvt instruction)
DEV uint16_t f2b(float f) {
  __hip_bfloat16 h = __float2bfloat16(f);
  return *(uint16_t*)&h;
}
// pack two floats into a bf16x2 word
DEV uint32_t pkbf2(float a, float b) {
  return (uint32_t)f2b(a) | ((uint32_t)f2b(b) << 16);
}
// pack four floats into 4x bf16 (uint64)
DEV uint64_t pkbf4(float a, float b, float c, float d) {
  return (uint64_t)pkbf2(a, b) | ((uint64_t)pkbf2(c, d) << 32);
}

// async global->LDS, 16B per lane. LDS base must be wave-uniform; HW writes
// base + lane*16. Global source address is per-lane.
DEV void gload_lds16(const void* g, void* l) {
  __builtin_amdgcn_global_load_lds(
      (const __attribute__((address_space(1))) void*)g,
      (__attribute__((address_space(3))) void*)l, 16, 0, 0);
}

// scale a bf16x8 by a constant (via fp32, RNE back to bf16)
DEV bf16x8 scale8(bf16x8 v, float sc) {
  union { bf16x8 b; uint16_t u[8]; } in, out;
  in.b = v;
#pragma unroll
  for (int i = 0; i < 8; i++) {
    float x = __uint_as_float(((uint32_t)in.u[i]) << 16);
    out.u[i] = f2b(x * sc);
  }
  return out.b;
}

// ------------------------------------------------------- merged prep kernel
// One dispatch: cast_x, transpose(Wq|Wk|Wv), transpose(Wo), transpose(W1),
// transpose(W2), concat3(biases). Vectorized global I/O: float4 loads,
// uint64 (4x bf16) stores. blocks: [0,4096) cast | [4096,7168) w3 |
// [7168,8192) Wo | [8192,12288) W1 | [12288,16384) W2 | [16384,16396) concat
__global__ __launch_bounds__(256) void prep_all(
    const float* __restrict__ x, uint16_t* __restrict__ xb,
    const float* __restrict__ Wq, const float* __restrict__ Wk,
    const float* __restrict__ Wv, uint16_t* __restrict__ wqkt,
    const float* __restrict__ Wo, uint16_t* __restrict__ wot,
    const float* __restrict__ W1, uint16_t* __restrict__ w1t,
    const float* __restrict__ W2, uint16_t* __restrict__ w2t,
    const float* __restrict__ bq, const float* __restrict__ bk,
    const float* __restrict__ bv, float* __restrict__ bqkv) {
  __shared__ float t[32][33];
  int bid = blockIdx.x, tid = threadIdx.x;
  if (bid < 4096) {               // ---- cast x -> bf16
    int i = bid * 256 + tid;
    float4 v = ((const float4*)x)[i];
    ((uint64_t*)xb)[i] = pkbf4(v.x, v.y, v.z, v.w);
    return;
  }
  if (bid >= 16384) {             // ---- bias concat
    int i = (bid - 16384) * 256 + tid;
    if (i < 3072)
      bqkv[i] = i < 1024 ? bq[i] : (i < 2048 ? bk[i - 1024] : bv[i - 2048]);
    return;
  }
  // ---- weight transpose fp32[R][C] -> bf16[C][R], 32x32 tile
  const float* src;
  uint16_t* dst;
  int R, C, bx, by;
  if (bid < 8192) {
    int local = bid - 4096;
    if (local < 3072) {           // Wq|Wk|Wv (1024x1024 each)
      int z = local >> 10, rem = local & 1023;
      src = z == 0 ? Wq : (z == 1 ? Wk : Wv);
      dst = wqkt + (size_t)z * 1024 * 1024;
      R = 1024; C = 1024; bx = rem & 31; by = rem >> 5;
    } else {                      // Wo
      int rem = local - 3072;
      src = Wo; dst = wot; R = 1024; C = 1024; bx = rem & 31; by = rem >> 5;
    }
  } else if (bid < 12288) {       // W1: [1024][4096] -> [4096][1024]
    int rem = bid - 8192;
    src = W1; dst = w1t; R = 1024; C = 4096; bx = rem & 127; by = rem >> 7;
  } else {                        // W2: [4096][1024] -> [1024][4096]
    int rem = bid - 12288;
    src = W2; dst = w2t; R = 4096; C = 1024; bx = rem & 31; by = rem >> 5;
  }
  int c0 = bx * 32, r0 = by * 32;
  // load: float4 per thread (16B/lane)
  int lrow = tid >> 3, lc = (tid & 7) * 4;
  float4 v = *(const float4*)&src[(size_t)(r0 + lrow) * C + c0 + lc];
  t[lrow][lc] = v.x; t[lrow][lc + 1] = v.y;
  t[lrow][lc + 2] = v.z; t[lrow][lc + 3] = v.w;
  __syncthreads();
  // store: 4x bf16 per thread along R (8B/lane)
  int cr = tid >> 3, rq = (tid & 7) * 4;
  uint64_t r = pkbf4(t[rq][cr], t[rq + 1][cr], t[rq + 2][cr], t[rq + 3][cr]);
  *(uint64_t*)&dst[(size_t)(c0 + cr) * R + r0 + rq] = r;
}

// ------------------------------------------------------------------------- GEMM
// 128x128 tile, 4 waves, BK=32 linear / BK=64 swizzled, 2-phase pipeline.
// NSPLIT: K split; split sp writes partial sp at Cv + sp*M*N (bf16 for MODE=1).
// QKV=1: N=3072 fused projection; column tiles >= 2048 are the V head-matrix
// and are written TRANSPOSED to vt[bh][d][s] (4 consecutive s per lane ->
// single packed uint64 store; 64B vt lines fully covered within one block).
// MODE: 0 = fp32 out, 1 = bf16 out, 2 = bf16 out + relu
template <int MODE, int NSPLIT, int BK, int QKV>
__global__ __launch_bounds__(256) void gemm_bt(
    const uint16_t* __restrict__ A, const uint16_t* __restrict__ Bt,
    const float* __restrict__ bias, void* __restrict__ Cv,
    uint16_t* __restrict__ vt, int M, int N, int K, int nx) {
  __shared__ uint16_t As[2][128 * BK];
  __shared__ uint16_t Bs[2][128 * BK];
  int nwg = gridDim.x, bid = blockIdx.x;
  int cpx = nwg >> 3;
  int swzb = (bid & 7) * cpx + (bid >> 3);  // XCD (bid&7) owns contiguous chunk
  int ntile = nwg / NSPLIT;
  int sp = swzb / ntile, r = swzb % ntile;
  int n0 = (r % nx) * 128, m0 = (r / nx) * 128;
  int Klen = K / NSPLIT;
  int tid = threadIdx.x, w = tid >> 6, l = tid & 63;
  int wr = w >> 1, wc = w & 1;
  int lr = l & 15, lg = l >> 4, lk8 = lg * 8;
  f32x4 acc[4][4] = {};
  const uint16_t* Ab = A + (size_t)m0 * K + sp * Klen;
  const uint16_t* Bb = Bt + (size_t)n0 * K + sp * Klen;

  auto stage = [&](int buf, int k0) {
    if (BK == 32) {
#pragma unroll
      for (int i = 0; i < 2; i++) {
        int c = 2 * w + i;             // 8 chunks of 16 rows
        int rr = c * 16 + (l >> 2);
        gload_lds16(Ab + (size_t)rr * K + k0 + (l & 3) * 8, &As[buf][c * 512]);
        gload_lds16(Bb + (size_t)rr * K + k0 + (l & 3) * 8, &Bs[buf][c * 512]);
      }
    } else {
      int colb = (((l & 7) ^ ((l >> 3) & 7)) << 4);  // inverse-swizzled source
#pragma unroll
      for (int i = 0; i < 4; i++) {
        int c = 4 * w + i;             // 16 chunks of 8 rows
        int rr = c * 8 + (l >> 3);
        gload_lds16((const uint8_t*)(Ab + (size_t)rr * K + k0) + colb,
                    &As[buf][c * 512]);
        gload_lds16((const uint8_t*)(Bb + (size_t)rr * K + k0) + colb,
                    &Bs[buf][c * 512]);
      }
    }
  };

  stage(0, 0);
  __syncthreads();

  for (int k0 = 0; k0 < Klen; k0 += BK) {
    int cur = (k0 / BK) & 1;
    if (k0 + BK < Klen) stage(cur ^ 1, k0 + BK);  // prefetch next tile
    if (BK == 32) {
      bf16x8 af[4], bf[4];
#pragma unroll
      for (int m = 0; m < 4; m++)
        af[m] = *(const bf16x8*)&As[cur][(wr * 64 + m * 16 + lr) * 32 + lk8];
#pragma unroll
      for (int n = 0; n < 4; n++)
        bf[n] = *(const bf16x8*)&Bs[cur][(wc * 64 + n * 16 + lr) * 32 + lk8];
#pragma unroll
      for (int m = 0; m < 4; m++)
#pragma unroll
        for (int n = 0; n < 4; n++)
          acc[m][n] = __builtin_amdgcn_mfma_f32_16x16x32_bf16(af[m], bf[n], acc[m][n], 0, 0, 0);
    } else {
      int sw = (lr & 7) << 4;
#pragma unroll
      for (int ks = 0; ks < 2; ks++) {
        int off = ((ks << 6) | (lg << 4)) ^ sw;  // swizzled read (matches source)
        bf16x8 af[4], bf[4];
#pragma unroll
        for (int m = 0; m < 4; m++)
          af[m] = *(const bf16x8*)((const uint8_t*)&As[cur][(wr * 64 + m * 16 + lr) * 64] + off);
#pragma unroll
        for (int n = 0; n < 4; n++)
          bf[n] = *(const bf16x8*)((const uint8_t*)&Bs[cur][(wc * 64 + n * 16 + lr) * 64] + off);
#pragma unroll
        for (int m = 0; m < 4; m++)
#pragma unroll
          for (int n = 0; n < 4; n++)
            acc[m][n] = __builtin_amdgcn_mfma_f32_16x16x32_bf16(af[m], bf[n], acc[m][n], 0, 0, 0);
      }
    }
    __syncthreads();  // drains prefetch vmcnt + all waves done with cur
  }

  int g4 = lg * 4;
  if (QKV && n0 >= 2048) {
    // V tile -> vt[bh][d][s], packed 4x bf16 along s
#pragma unroll
    for (int m = 0; m < 4; m++) {
      int row = m0 + wr * 64 + m * 16 + g4;   // s-range base (4 consecutive)
      int b_ = row >> 11, s_ = row & 2047;
#pragma unroll
      for (int n = 0; n < 4; n++) {
        int c = n0 - 2048 + wc * 64 + n * 16 + lr;   // h*64 + d
        float bv = bias[n0 + wc * 64 + n * 16 + lr];
        uint64_t pk = pkbf4(acc[m][n][0] + bv, acc[m][n][1] + bv,
                            acc[m][n][2] + bv, acc[m][n][3] + bv);
        size_t vidx = ((size_t)(b_ * 16 + (c >> 6))) * 131072 +
                      (size_t)(c & 63) * 2048 + s_;
        *(uint64_t*)&vt[vidx] = pk;
      }
    }
    return;
  }
#pragma unroll
  for (int m = 0; m < 4; m++) {
    int row = m0 + wr * 64 + m * 16 + g4;
#pragma unroll
    for (int n = 0; n < 4; n++) {
      int col = n0 + wc * 64 + n * 16 + lr;
      float bv = (NSPLIT == 1 || sp == 0) ? bias[col] : 0.f;
#pragma unroll
      for (int j = 0; j < 4; j++) {
        float v = acc[m][n][j] + bv;
        if (MODE == 2) v = fmaxf(v, 0.f);
        size_t idx = (size_t)sp * M * N + (size_t)(row + j) * N + col;
        if (MODE == 0) ((float*)Cv)[idx] = v;
        else           ((uint16_t*)Cv)[idx] = f2b(v);
      }
    }
  }
}

// ---------------------------------------------------- GEMM 256x256, phase-split
// (round-12 verified schedule) + NSPLIT split-K (contiguous bf16 partials).
// 512 thr = 8 waves, BK=64, 4 phases/K-tile, counted vmcnt drain at phase 3.
// NOTE: needs nt = Klen/64 >= 8 to amortize the prologue (round-16 lesson).
template <int MODE, int NSPLIT>
__global__ __launch_bounds__(512, 2) void gemm256(
    const uint16_t* __restrict__ A, const uint16_t* __restrict__ Bt,
    const float* __restrict__ bias, void* __restrict__ Cv,
    int M, int N, int K, int nx) {
  __shared__ uint16_t As[2][256 * 64];
  __shared__ uint16_t Bs[2][256 * 64];
  int nwg = gridDim.x, bid = blockIdx.x;
  int cpx = nwg >> 3;
  int swzb = (bid & 7) * cpx + (bid >> 3);
  int ntile = nwg / NSPLIT;
  int sp = swzb / ntile, rr0 = swzb % ntile;
  int n0 = (rr0 % nx) * 256, m0 = (rr0 / nx) * 256;
  int Klen = K / NSPLIT;
  int tid = threadIdx.x, w = tid >> 6, l = tid & 63;
  int wr = w >> 2, wc = w & 3;
  int lr = l & 15, lg = l >> 4;
  f32x4 acc[8][4] = {};
  const uint16_t* Ab = A + (size_t)m0 * K + sp * Klen;
  const uint16_t* Bb = Bt + (size_t)n0 * K + sp * Klen;
  int colb = (((l & 7) ^ (l >> 3)) << 4);  // inverse-swizzled source col
  int srl = l >> 3;                        // lane sub-row 0..7

  auto stageH = [&](int buf, int k0, int h) {
    const uint16_t* base = (h < 2) ? Ab : Bb;
    uint16_t* lds = (h < 2) ? &As[buf][0] : &Bs[buf][0];
    int hh = (h & 1) * 128;
#pragma unroll
    for (int j = 0; j < 2; j++) {
      int rr = hh + j * 64 + w * 8;  // wave-uniform row base
      gload_lds16((const uint8_t*)(base + (size_t)(rr + srl) * K + k0) + colb,
                  &lds[rr * 64]);
    }
  };

#pragma unroll
  for (int h = 0; h < 4; h++) stageH(0, 0, h);
  asm volatile("s_waitcnt vmcnt(0)" ::: "memory");
  __builtin_amdgcn_s_barrier();

  int nt = Klen >> 6;
  int swr = (lr & 7) << 4;
  for (int t = 0; t < nt; t++) {
    int buf = t & 1;
    bf16x8 bfr[2][4];
#pragma unroll
    for (int ks = 0; ks < 2; ks++) {
#pragma unroll
      for (int mq = 0; mq < 2; mq++) {
        const int ph = ks * 2 + mq;
        int off = ((ks << 6) | (lg << 4)) ^ swr;
        bf16x8 af[4];
#pragma unroll
        for (int m = 0; m < 4; m++) {
          int row = wr * 128 + (mq * 4 + m) * 16 + lr;
          af[m] = *(const bf16x8*)((const uint8_t*)&As[buf][row * 64] + off);
        }
        if (mq == 0) {
#pragma unroll
          for (int n = 0; n < 4; n++) {
            int row = wc * 64 + n * 16 + lr;
            bfr[ks][n] = *(const bf16x8*)((const uint8_t*)&Bs[buf][row * 64] + off);
          }
        }
        if (t + 1 < nt) {
          if (ph == 0) { stageH(buf ^ 1, (t + 1) * 64, 0); stageH(buf ^ 1, (t + 1) * 64, 1); }
          if (ph == 1) { stageH(buf ^ 1, (t + 1) * 64, 2); stageH(buf ^ 1, (t + 1) * 64, 3); }
        }
        __builtin_amdgcn_s_barrier();
        asm volatile("s_waitcnt lgkmcnt(0)" ::: "memory");
        __builtin_amdgcn_sched_barrier(0);
        __builtin_amdgcn_s_setprio(1);
#pragma unroll
        for (int m = 0; m < 4; m++)
#pragma unroll
          for (int n = 0; n < 4; n++)
            acc[mq * 4 + m][n] = __builtin_amdgcn_mfma_f32_16x16x32_bf16(
                af[m], bfr[ks][n], acc[mq * 4 + m][n], 0, 0, 0);
        __builtin_amdgcn_s_setprio(0);
        if (ph == 3) asm volatile("s_waitcnt vmcnt(0)" ::: "memory");  // t+1 loads done
        __builtin_amdgcn_s_barrier();
      }
    }
  }

#pragma unroll
  for (int m = 0; m < 8; m++) {
    int row = m0 + wr * 128 + m * 16 + lg * 4;
#pragma unroll
    for (int n = 0; n < 4; n++) {
      int col = n0 + wc * 64 + n * 16 + lr;
      float bv = (NSPLIT == 1 || sp == 0) ? bias[col] : 0.f;
#pragma unroll
      for (int j = 0; j < 4; j++) {
        float v = acc[m][n][j] + bv;
        if (MODE == 2) v = fmaxf(v, 0.f);
        size_t idx = (size_t)sp * M * N + (size_t)(row + j) * N + col;
        if (MODE == 0) ((float*)Cv)[idx] = v;
        else           ((uint16_t*)Cv)[idx] = f2b(v);
      }
    }
  }
}

// --------------------------------------------------------------- fused attention
// (round-11/12 proven: 512 blocks, 4 waves, 2 Q-frags/wave, 16x16 MFMA,
// KVBLK=128 double-buffered, XOR-swizzle, no-max softmax, deferred denominator)
__global__ __launch_bounds__(256, 2) void attn_fused(
    const uint16_t* __restrict__ qkv, const uint16_t* __restrict__ Vt,
    uint16_t* __restrict__ outb) {
  constexpr int LQ = 3072;
  constexpr float SC = 0.18033688f;  // 0.125 * log2(e)
  int L = blockIdx.x;
  int qb = (L >> 3) & 15;
  int bh = (L & 7) + 8 * (L >> 7);
  int b = bh >> 4, h = bh & 15;
  int w = threadIdx.x >> 6, l = threadIdx.x & 63;
  int lr = l & 15, lg = l >> 4;
  int qbase = qb * 128 + w * 32;

  __shared__ uint16_t Kbuf[2][2][64 * 64];  // [dbuf][sub][key-row][d]
  __shared__ uint16_t Vbuf[2][2][64 * 64];  // [dbuf][sub][d-row][key]
  __shared__ uint16_t Plds[4][2][16 * 64];  // per-wave, per-qfrag P tiles
  uint16_t* PwA = &Plds[w][0][0];
  uint16_t* PwB = &Plds[w][1][0];

  const uint16_t* qrowA = qkv + (size_t)(b * 2048 + qbase + lr) * LQ + h * 64;
  const uint16_t* qrowB = qrowA + (size_t)16 * LQ;
  bf16x8 qA0 = scale8(*(const bf16x8*)(qrowA + lg * 8), SC);
  bf16x8 qA1 = scale8(*(const bf16x8*)(qrowA + 32 + lg * 8), SC);
  bf16x8 qB0 = scale8(*(const bf16x8*)(qrowB + lg * 8), SC);
  bf16x8 qB1 = scale8(*(const bf16x8*)(qrowB + 32 + lg * 8), SC);

  float rsA = 0.f, rsB = 0.f;
  f32x4 oA[4] = {}, oB[4] = {};

  const uint8_t* kq = (const uint8_t*)qkv;
  const uint8_t* vq = (const uint8_t*)Vt;
  int colb = (((l & 7) ^ ((l >> 3) & 7)) << 4);
  int Rl = w * 16 + (l >> 3);

  auto stageKV = [&](int buf, int kb) {
#pragma unroll
    for (int s2 = 0; s2 < 2; s2++) {
#pragma unroll
      for (int c2 = 0; c2 < 2; c2++) {
        int R = Rl + c2 * 8;
        const uint8_t* ks =
            kq + ((size_t)(b * 2048 + kb + s2 * 64 + R) * LQ + 1024 + h * 64) * 2 + colb;
        gload_lds16(ks, &Kbuf[buf][s2][(w * 16 + c2 * 8) * 64]);
        const uint8_t* vs =
            vq + ((size_t)(bh * 64 + R) * 2048 + kb + s2 * 64) * 2 + colb;
        gload_lds16(vs, &Vbuf[buf][s2][(w * 16 + c2 * 8) * 64]);
      }
    }
  };

  stageKV(0, 0);
  __syncthreads();

  int swz = (lr & 7) << 4;
  for (int kb = 0; kb < 2048; kb += 128) {
    int cur = (kb >> 7) & 1;
    if (kb + 128 < 2048) stageKV(cur ^ 1, kb + 128);

#pragma unroll
    for (int s2 = 0; s2 < 2; s2++) {
      const uint8_t* Kb = (const uint8_t*)Kbuf[cur][s2];
      const uint8_t* Vb = (const uint8_t*)Vbuf[cur][s2];
      f32x4 sA[4], sB[4];
      __builtin_amdgcn_s_setprio(1);
#pragma unroll
      for (int t = 0; t < 4; t++) {
        const uint8_t* rb = Kb + (16 * t + lr) * 128;
        bf16x8 k0 = *(const bf16x8*)(rb + ((lg << 4) ^ swz));
        bf16x8 k1 = *(const bf16x8*)(rb + ((64 | (lg << 4)) ^ swz));
        f32x4 zA = {};
        zA = __builtin_amdgcn_mfma_f32_16x16x32_bf16(k0, qA0, zA, 0, 0, 0);
        zA = __builtin_amdgcn_mfma_f32_16x16x32_bf16(k1, qA1, zA, 0, 0, 0);
        sA[t] = zA;
        f32x4 zB = {};
        zB = __builtin_amdgcn_mfma_f32_16x16x32_bf16(k0, qB0, zB, 0, 0, 0);
        zB = __builtin_amdgcn_mfma_f32_16x16x32_bf16(k1, qB1, zB, 0, 0, 0);
        sB[t] = zB;
      }
      __builtin_amdgcn_s_setprio(0);
#pragma unroll
      for (int t = 0; t < 4; t++) {
        float a0 = __builtin_amdgcn_exp2f(sA[t][0]);
        float a1 = __builtin_amdgcn_exp2f(sA[t][1]);
        float a2 = __builtin_amdgcn_exp2f(sA[t][2]);
        float a3 = __builtin_amdgcn_exp2f(sA[t][3]);
        rsA += (a0 + a1) + (a2 + a3);
        uint2 pa;
        pa.x = pkbf2(a0, a1);
        pa.y = pkbf2(a2, a3);
        *(uint2*)((uint8_t*)PwA + lr * 128 + ((t * 32 + lg * 8) ^ swz)) = pa;
        float b0 = __builtin_amdgcn_exp2f(sB[t][0]);
        float b1 = __builtin_amdgcn_exp2f(sB[t][1]);
        float b2 = __builtin_amdgcn_exp2f(sB[t][2]);
        float b3 = __builtin_amdgcn_exp2f(sB[t][3]);
        rsB += (b0 + b1) + (b2 + b3);
        uint2 pb;
        pb.x = pkbf2(b0, b1);
        pb.y = pkbf2(b2, b3);
        *(uint2*)((uint8_t*)PwB + lr * 128 + ((t * 32 + lg * 8) ^ swz)) = pb;
      }
      __builtin_amdgcn_wave_barrier();  // keep ds_reads after ds_writes (same-wave order)
      bf16x8 pA0 = *(const bf16x8*)((const uint8_t*)PwA + lr * 128 + ((lg << 4) ^ swz));
      bf16x8 pA1 = *(const bf16x8*)((const uint8_t*)PwA + lr * 128 + ((64 | (lg << 4)) ^ swz));
      bf16x8 pB0 = *(const bf16x8*)((const uint8_t*)PwB + lr * 128 + ((lg << 4) ^ swz));
      bf16x8 pB1 = *(const bf16x8*)((const uint8_t*)PwB + lr * 128 + ((64 | (lg << 4)) ^ swz));
      __builtin_amdgcn_s_setprio(1);
#pragma unroll
      for (int t = 0; t < 4; t++) {
        const uint8_t* rb = Vb + (16 * t + lr) * 128;
        bf16x8 v0 = *(const bf16x8*)(rb + ((lg << 4) ^ swz));
        bf16x8 v1 = *(const bf16x8*)(rb + ((64 | (lg << 4)) ^ swz));
        oA[t] = __builtin_amdgcn_mfma_f32_16x16x32_bf16(v0, pA0, oA[t], 0, 0, 0);
        oA[t] = __builtin_amdgcn_mfma_f32_16x16x32_bf16(v1, pA1, oA[t], 0, 0, 0);
        oB[t] = __builtin_amdgcn_mfma_f32_16x16x32_bf16(v0, pB0, oB[t], 0, 0, 0);
        oB[t] = __builtin_amdgcn_mfma_f32_16x16x32_bf16(v1, pB1, oB[t], 0, 0, 0);
      }
      __builtin_amdgcn_s_setprio(0);
      if (s2 == 0) __builtin_amdgcn_wave_barrier();  // P reuse: reads before next writes
    }
    __syncthreads();  // drains stage vmcnt + all waves done reading cur
  }
  rsA += __shfl_xor(rsA, 16);
  rsA += __shfl_xor(rsA, 32);
  rsB += __shfl_xor(rsB, 16);
  rsB += __shfl_xor(rsB, 32);
  float invA = 1.f / rsA, invB = 1.f / rsB;
  uint16_t* orowA = outb + (size_t)(b * 2048 + qbase + lr) * 1024 + h * 64;
  uint16_t* orowB = orowA + (size_t)16 * 1024;
#pragma unroll
  for (int t = 0; t < 4; t++) {
    uint2 ra;
    ra.x = pkbf2(oA[t][0] * invA, oA[t][1] * invA);
    ra.y = pkbf2(oA[t][2] * invA, oA[t][3] * invA);
    *(uint2*)(orowA + t * 16 + lg * 4) = ra;
    uint2 rb2;
    rb2.x = pkbf2(oB[t][0] * invB, oB[t][1] * invB);
    rb2.y = pkbf2(oB[t][2] * invB, oB[t][3] * invB);
    *(uint2*)(orowB + t * 16 + lg * 4) = rb2;
  }
}

// ------------------------------------------- LayerNorm(x + sum of NPART partials)
// XBF: xr is bf16. parts: NPART contiguous bf16 [4096][1024] partials.
template <int XBF, int WF32, int WB16, int NPART>
__global__ __launch_bounds__(256) void ln_res(
    const void* __restrict__ xr, const uint16_t* __restrict__ parts,
    const float* __restrict__ gam, const float* __restrict__ bet,
    float* __restrict__ of32, uint16_t* __restrict__ ob16) {
  int row = blockIdx.x, t = threadIdx.x;
  int w = t >> 6, l = t & 63;
  float v0, v1, v2, v3;
  if (XBF) {
    uint2 u = ((const uint2*)((const uint16_t*)xr + (size_t)row * 1024))[t];
    v0 = __uint_as_float((u.x & 0xffffu) << 16);
    v1 = __uint_as_float(u.x & 0xffff0000u);
    v2 = __uint_as_float((u.y & 0xffffu) << 16);
    v3 = __uint_as_float(u.y & 0xffff0000u);
  } else {
    float4 xv = ((const float4*)((const float*)xr + (size_t)row * 1024))[t];
    v0 = xv.x; v1 = xv.y; v2 = xv.z; v3 = xv.w;
  }
#pragma unroll
  for (int p = 0; p < NPART; p++) {
    uint2 u = ((const uint2*)(parts + (size_t)p * 4096 * 1024 +
                              (size_t)row * 1024))[t];
    v0 += __uint_as_float((u.x & 0xffffu) << 16);
    v1 += __uint_as_float(u.x & 0xffff0000u);
    v2 += __uint_as_float((u.y & 0xffffu) << 16);
    v3 += __uint_as_float(u.y & 0xffff0000u);
  }
  float s = v0 + v1 + v2 + v3;
  float sq = v0 * v0 + v1 * v1 + v2 * v2 + v3 * v3;
#pragma unroll
  for (int d = 1; d < 64; d <<= 1) {
    s += __shfl_xor(s, d);
    sq += __shfl_xor(sq, d);
  }
  __shared__ float red[8];
  if (l == 0) { red[w] = s; red[4 + w] = sq; }
  __syncthreads();
  s = red[0] + red[1] + red[2] + red[3];
  sq = red[4] + red[5] + red[6] + red[7];
  float mean = s * (1.f / 1024.f);
  float var = sq * (1.f / 1024.f) - mean * mean;
  float rstd = rsqrtf(var + 1e-5f);
  float4 gv = ((const float4*)gam)[t];
  float4 bv = ((const float4*)bet)[t];
  float y0 = (v0 - mean) * rstd * gv.x + bv.x;
  float y1 = (v1 - mean) * rstd * gv.y + bv.y;
  float y2 = (v2 - mean) * rstd * gv.z + bv.z;
  float y3 = (v3 - mean) * rstd * gv.w + bv.w;
  if (WF32) {
    float4 yv; yv.x = y0; yv.y = y1; yv.z = y2; yv.w = y3;
    ((float4*)(of32 + (size_t)row * 1024))[t] = yv;
  }
  if (WB16) {
    uint2 r;
    r.x = pkbf2(y0, y1);
    r.y = pkbf2(y2, y3);
    ((uint2*)(ob16 + (size_t)row * 1024))[t] = r;
  }
}

// ---------------------------------------------------------------- workspace map
static constexpr size_t OFF_XB    = 0;                          // 8 MB x_bf16 (live thru LN1)
static constexpr size_t OFF_WQKVT = (size_t)8 << 20;            // 6 MB [3072][1024]
static constexpr size_t OFF_WOT   = (size_t)14 << 20;           // 2 MB [1024][1024]
static constexpr size_t OFF_W1T   = (size_t)16 << 20;           // 8 MB [4096][1024]
static constexpr size_t OFF_W2T   = (size_t)24 << 20;           // 8 MB [1024][4096]
static constexpr size_t OFF_BIAS  = (size_t)32 << 20;           // 12 KB f32 (pad 64K)
static constexpr size_t OFF_QKV   = OFF_BIAS + ((size_t)64 << 10);  // 24 MB; +VT reused: H (32MB)
static constexpr size_t OFF_VT    = OFF_QKV + ((size_t)24 << 20);   // 8 MB [32][64][2048]
static constexpr size_t OFF_PROJ  = OFF_VT + ((size_t)8 << 20);     // 32 MB: 4x bf16 partials
static constexpr size_t OFF_LN1B  = OFF_PROJ + ((size_t)32 << 20);  // 8 MB bf16 trunk
static constexpr size_t OFF_ATTN  = OFF_LN1B + ((size_t)8 << 20);   // 8 MB attn out
// total ~120 MB

extern "C" void kernel_launch(void* const* d_in, const int* in_sizes, int n_in,
                              void* d_out, int out_size, void* d_ws, size_t ws_size,
                              hipStream_t stream) {
  const float* x   = (const float*)d_in[0];
  const float* Wq  = (const float*)d_in[1];
  const float* bq  = (const float*)d_in[2];
  const float* Wk  = (const float*)d_in[3];
  const float* bk  = (const float*)d_in[4];
  const float* Wv  = (const float*)d_in[5];
  const float* bv  = (const float*)d_in[6];
  const float* Wo  = (const float*)d_in[7];
  const float* bo  = (const float*)d_in[8];
  const float* W1  = (const float*)d_in[9];
  const float* b1  = (const float*)d_in[10];
  const float* W2  = (const float*)d_in[11];
  const float* b2  = (const float*)d_in[12];
  const float* g1  = (const float*)d_in[13];
  const float* be1 = (const float*)d_in[14];
  const float* g2  = (const float*)d_in[15];
  const float* be2 = (const float*)d_in[16];
  float* out = (float*)d_out;
  uint8_t* ws = (uint8_t*)d_ws;

  uint16_t* xb    = (uint16_t*)(ws + OFF_XB);
  uint16_t* wqkt  = (uint16_t*)(ws + OFF_WQKVT);
  uint16_t* wot   = (uint16_t*)(ws + OFF_WOT);
  uint16_t* w1t   = (uint16_t*)(ws + OFF_W1T);
  uint16_t* w2t   = (uint16_t*)(ws + OFF_W2T);
  float*    bqkv  = (float*)(ws + OFF_BIAS);
  uint16_t* qkvb  = (uint16_t*)(ws + OFF_QKV);
  uint16_t* vt    = (uint16_t*)(ws + OFF_VT);
  uint16_t* proj  = (uint16_t*)(ws + OFF_PROJ);   // up to 4x contiguous partials
  uint16_t* ln1b  = (uint16_t*)(ws + OFF_LN1B);
  uint16_t* attnb = (uint16_t*)(ws + OFF_ATTN);
  uint16_t* hbuf  = (uint16_t*)(ws + OFF_QKV);  // alias: qkv+vt dead after attention

  // 1. merged prep: cast x, all weight transposes, bias concat (one dispatch)
  prep_all<<<16396, 256, 0, stream>>>(x, xb, Wq, Wk, Wv, wqkt, Wo, wot,
                                      W1, w1t, W2, w2t, bq, bk, bv, bqkv);
  // 2. fused QKV projection; V columns written directly transposed to vt
  gemm_bt<1, 1, 32, 1><<<768, 256, 0, stream>>>(xb, wqkt, bqkv, qkvb, vt,
                                                4096, 3072, 1024, 24);
  // 3. fused attention (512 blocks, 16x16 MFMA, KVBLK=128)
  attn_fused<<<512, 256, 0, stream>>>(qkvb, vt, attnb);
  // 4. output projection: 128x128 split-K x4, BK=32 (1024 blocks, 4/CU TLP)
  gemm_bt<1, 4, 32, 0><<<1024, 256, 0, stream>>>(attnb, wot, bo, proj, nullptr,
                                                 4096, 1024, 1024, 8);
  // 5. LN1(xb + p0..p3) -> bf16 trunk only
  ln_res<1, 0, 1, 4><<<4096, 256, 0, stream>>>(xb, proj, g1, be1,
                                               nullptr, ln1b);
  // 6. MLP1 + relu -> bf16, 256x256 phase-split (256 blocks, 1/CU, nt=16)
  gemm256<2, 1><<<256, 512, 0, stream>>>(ln1b, w1t, b1, hbuf,
                                         4096, 4096, 1024, 16);
  // 7. MLP2: 256x256 phase-split, split-K x4 (256 blocks, nt=16)
  gemm256<1, 4><<<256, 512, 0, stream>>>(hbuf, w2t, b2, proj,
                                         4096, 1024, 4096, 4);
  // 8. LN2(ln1b + p0..p3) -> d_out fp32
  ln_res<1, 1, 0, 4><<<4096, 256, 0, stream>>>(ln1b, proj, g2, be2,
                                               out, nullptr);
}

// Round 22
// 207.103 us; speedup vs baseline: 1.0410x; 1.0410x over previous
//
#include <hip/hip_runtime.h>
#include <hip/hip_bf16.h>
#include <cstdint>

#define DEV __device__ __forceinline__

typedef __attribute__((ext_vector_type(8))) __bf16 bf16x8;
typedef __attribute__((ext_vector_type(4))) float f32x4;

// fp32 -> bf16 via HW cvt (single v_cvt instruction)
DEV uint16_t f2b(float f) {
  __hip_bfloat16 h = __float2bfloat16(f);
  return *(uint16_t*)&h;
}
// pack two floats into a bf16x2 word
DEV uint32_t pkbf2(float a, float b) {
  return (uint32_t)f2b(a) | ((uint32_t)f2b(b) << 16);
}
// pack four floats into 4x bf16 (uint64)
DEV uint64_t pkbf4(float a, float b, float c, float d) {
  return (uint64_t)pkbf2(a, b) | ((uint64_t)pkbf2(c, d) << 32);
}

// async global->LDS, 16B per lane. LDS base must be wave-uniform; HW writes
// base + lane*16. Global source address is per-lane.
DEV void gload_lds16(const void* g, void* l) {
  __builtin_amdgcn_global_load_lds(
      (const __attribute__((address_space(1))) void*)g,
      (__attribute__((address_space(3))) void*)l, 16, 0, 0);
}

// scale a bf16x8 by a constant (via fp32, RNE back to bf16)
DEV bf16x8 scale8(bf16x8 v, float sc) {
  union { bf16x8 b; uint16_t u[8]; } in, out;
  in.b = v;
#pragma unroll
  for (int i = 0; i < 8; i++) {
    float x = __uint_as_float(((uint32_t)in.u[i]) << 16);
    out.u[i] = f2b(x * sc);
  }
  return out.b;
}

// ------------------------------------------------------- merged prep kernel
// One dispatch: cast_x, transpose(Wq|Wk|Wv), transpose(Wo), transpose(W1),
// transpose(W2), concat3(biases). Vectorized global I/O: float4 loads,
// uint64 (4x bf16) stores. blocks: [0,4096) cast | [4096,7168) w3 |
// [7168,8192) Wo | [8192,12288) W1 | [12288,16384) W2 | [16384,16396) concat
__global__ __launch_bounds__(256) void prep_all(
    const float* __restrict__ x, uint16_t* __restrict__ xb,
    const float* __restrict__ Wq, const float* __restrict__ Wk,
    const float* __restrict__ Wv, uint16_t* __restrict__ wqkt,
    const float* __restrict__ Wo, uint16_t* __restrict__ wot,
    const float* __restrict__ W1, uint16_t* __restrict__ w1t,
    const float* __restrict__ W2, uint16_t* __restrict__ w2t,
    const float* __restrict__ bq, const float* __restrict__ bk,
    const float* __restrict__ bv, float* __restrict__ bqkv) {
  __shared__ float t[32][33];
  int bid = blockIdx.x, tid = threadIdx.x;
  if (bid < 4096) {               // ---- cast x -> bf16
    int i = bid * 256 + tid;
    float4 v = ((const float4*)x)[i];
    ((uint64_t*)xb)[i] = pkbf4(v.x, v.y, v.z, v.w);
    return;
  }
  if (bid >= 16384) {             // ---- bias concat
    int i = (bid - 16384) * 256 + tid;
    if (i < 3072)
      bqkv[i] = i < 1024 ? bq[i] : (i < 2048 ? bk[i - 1024] : bv[i - 2048]);
    return;
  }
  // ---- weight transpose fp32[R][C] -> bf16[C][R], 32x32 tile
  const float* src;
  uint16_t* dst;
  int R, C, bx, by;
  if (bid < 8192) {
    int local = bid - 4096;
    if (local < 3072) {           // Wq|Wk|Wv (1024x1024 each)
      int z = local >> 10, rem = local & 1023;
      src = z == 0 ? Wq : (z == 1 ? Wk : Wv);
      dst = wqkt + (size_t)z * 1024 * 1024;
      R = 1024; C = 1024; bx = rem & 31; by = rem >> 5;
    } else {                      // Wo
      int rem = local - 3072;
      src = Wo; dst = wot; R = 1024; C = 1024; bx = rem & 31; by = rem >> 5;
    }
  } else if (bid < 12288) {       // W1: [1024][4096] -> [4096][1024]
    int rem = bid - 8192;
    src = W1; dst = w1t; R = 1024; C = 4096; bx = rem & 127; by = rem >> 7;
  } else {                        // W2: [4096][1024] -> [1024][4096]
    int rem = bid - 12288;
    src = W2; dst = w2t; R = 4096; C = 1024; bx = rem & 31; by = rem >> 5;
  }
  int c0 = bx * 32, r0 = by * 32;
  // load: float4 per thread (16B/lane)
  int lrow = tid >> 3, lc = (tid & 7) * 4;
  float4 v = *(const float4*)&src[(size_t)(r0 + lrow) * C + c0 + lc];
  t[lrow][lc] = v.x; t[lrow][lc + 1] = v.y;
  t[lrow][lc + 2] = v.z; t[lrow][lc + 3] = v.w;
  __syncthreads();
  // store: 4x bf16 per thread along R (8B/lane)
  int cr = tid >> 3, rq = (tid & 7) * 4;
  uint64_t r = pkbf4(t[rq][cr], t[rq + 1][cr], t[rq + 2][cr], t[rq + 3][cr]);
  *(uint64_t*)&dst[(size_t)(c0 + cr) * R + r0 + rq] = r;
}

// ------------------------------------------------------------------------- GEMM
// 128x128 tile, 4 waves, BK=32 linear / BK=64 swizzled, 2-phase pipeline.
// NSPLIT: K split; split sp writes partial sp at Cv + sp*M*N (bf16 for MODE=1).
// QKV=1: N=3072 fused projection; column tiles >= 2048 are the V head-matrix
// and are written TRANSPOSED to vt[bh][d][s] (4 consecutive s per lane ->
// single packed uint64 store; 64B vt lines fully covered within one block).
// MODE: 0 = fp32 out, 1 = bf16 out, 2 = bf16 out + relu
template <int MODE, int NSPLIT, int BK, int QKV>
__global__ __launch_bounds__(256) void gemm_bt(
    const uint16_t* __restrict__ A, const uint16_t* __restrict__ Bt,
    const float* __restrict__ bias, void* __restrict__ Cv,
    uint16_t* __restrict__ vt, int M, int N, int K, int nx) {
  __shared__ uint16_t As[2][128 * BK];
  __shared__ uint16_t Bs[2][128 * BK];
  int nwg = gridDim.x, bid = blockIdx.x;
  int cpx = nwg >> 3;
  int swzb = (bid & 7) * cpx + (bid >> 3);  // XCD (bid&7) owns contiguous chunk
  int ntile = nwg / NSPLIT;
  int sp = swzb / ntile, r = swzb % ntile;
  int n0 = (r % nx) * 128, m0 = (r / nx) * 128;
  int Klen = K / NSPLIT;
  int tid = threadIdx.x, w = tid >> 6, l = tid & 63;
  int wr = w >> 1, wc = w & 1;
  int lr = l & 15, lg = l >> 4, lk8 = lg * 8;
  f32x4 acc[4][4] = {};
  const uint16_t* Ab = A + (size_t)m0 * K + sp * Klen;
  const uint16_t* Bb = Bt + (size_t)n0 * K + sp * Klen;

  auto stage = [&](int buf, int k0) {
    if (BK == 32) {
#pragma unroll
      for (int i = 0; i < 2; i++) {
        int c = 2 * w + i;             // 8 chunks of 16 rows
        int rr = c * 16 + (l >> 2);
        gload_lds16(Ab + (size_t)rr * K + k0 + (l & 3) * 8, &As[buf][c * 512]);
        gload_lds16(Bb + (size_t)rr * K + k0 + (l & 3) * 8, &Bs[buf][c * 512]);
      }
    } else {
      int colb = (((l & 7) ^ ((l >> 3) & 7)) << 4);  // inverse-swizzled source
#pragma unroll
      for (int i = 0; i < 4; i++) {
        int c = 4 * w + i;             // 16 chunks of 8 rows
        int rr = c * 8 + (l >> 3);
        gload_lds16((const uint8_t*)(Ab + (size_t)rr * K + k0) + colb,
                    &As[buf][c * 512]);
        gload_lds16((const uint8_t*)(Bb + (size_t)rr * K + k0) + colb,
                    &Bs[buf][c * 512]);
      }
    }
  };

  stage(0, 0);
  __syncthreads();

  for (int k0 = 0; k0 < Klen; k0 += BK) {
    int cur = (k0 / BK) & 1;
    if (k0 + BK < Klen) stage(cur ^ 1, k0 + BK);  // prefetch next tile
    if (BK == 32) {
      bf16x8 af[4], bf[4];
#pragma unroll
      for (int m = 0; m < 4; m++)
        af[m] = *(const bf16x8*)&As[cur][(wr * 64 + m * 16 + lr) * 32 + lk8];
#pragma unroll
      for (int n = 0; n < 4; n++)
        bf[n] = *(const bf16x8*)&Bs[cur][(wc * 64 + n * 16 + lr) * 32 + lk8];
#pragma unroll
      for (int m = 0; m < 4; m++)
#pragma unroll
        for (int n = 0; n < 4; n++)
          acc[m][n] = __builtin_amdgcn_mfma_f32_16x16x32_bf16(af[m], bf[n], acc[m][n], 0, 0, 0);
    } else {
      int sw = (lr & 7) << 4;
#pragma unroll
      for (int ks = 0; ks < 2; ks++) {
        int off = ((ks << 6) | (lg << 4)) ^ sw;  // swizzled read (matches source)
        bf16x8 af[4], bf[4];
#pragma unroll
        for (int m = 0; m < 4; m++)
          af[m] = *(const bf16x8*)((const uint8_t*)&As[cur][(wr * 64 + m * 16 + lr) * 64] + off);
#pragma unroll
        for (int n = 0; n < 4; n++)
          bf[n] = *(const bf16x8*)((const uint8_t*)&Bs[cur][(wc * 64 + n * 16 + lr) * 64] + off);
#pragma unroll
        for (int m = 0; m < 4; m++)
#pragma unroll
          for (int n = 0; n < 4; n++)
            acc[m][n] = __builtin_amdgcn_mfma_f32_16x16x32_bf16(af[m], bf[n], acc[m][n], 0, 0, 0);
      }
    }
    __syncthreads();  // drains prefetch vmcnt + all waves done with cur
  }

  int g4 = lg * 4;
  if (QKV && n0 >= 2048) {
    // V tile -> vt[bh][d][s], packed 4x bf16 along s
#pragma unroll
    for (int m = 0; m < 4; m++) {
      int row = m0 + wr * 64 + m * 16 + g4;   // s-range base (4 consecutive)
      int b_ = row >> 11, s_ = row & 2047;
#pragma unroll
      for (int n = 0; n < 4; n++) {
        int c = n0 - 2048 + wc * 64 + n * 16 + lr;   // h*64 + d
        float bv = bias[n0 + wc * 64 + n * 16 + lr];
        uint64_t pk = pkbf4(acc[m][n][0] + bv, acc[m][n][1] + bv,
                            acc[m][n][2] + bv, acc[m][n][3] + bv);
        size_t vidx = ((size_t)(b_ * 16 + (c >> 6))) * 131072 +
                      (size_t)(c & 63) * 2048 + s_;
        *(uint64_t*)&vt[vidx] = pk;
      }
    }
    return;
  }
#pragma unroll
  for (int m = 0; m < 4; m++) {
    int row = m0 + wr * 64 + m * 16 + g4;
#pragma unroll
    for (int n = 0; n < 4; n++) {
      int col = n0 + wc * 64 + n * 16 + lr;
      float bv = (NSPLIT == 1 || sp == 0) ? bias[col] : 0.f;
#pragma unroll
      for (int j = 0; j < 4; j++) {
        float v = acc[m][n][j] + bv;
        if (MODE == 2) v = fmaxf(v, 0.f);
        size_t idx = (size_t)sp * M * N + (size_t)(row + j) * N + col;
        if (MODE == 0) ((float*)Cv)[idx] = v;
        else           ((uint16_t*)Cv)[idx] = f2b(v);
      }
    }
  }
}

// ---------------------------------------------------- GEMM 256x256, phase-split
// (round-12 verified schedule) + NSPLIT split-K (contiguous bf16 partials).
// 512 thr = 8 waves, BK=64, 4 phases/K-tile, counted vmcnt drain at phase 3.
// NOTE: needs nt = Klen/64 >= 8 to amortize the prologue (round-16 lesson).
template <int MODE, int NSPLIT>
__global__ __launch_bounds__(512, 2) void gemm256(
    const uint16_t* __restrict__ A, const uint16_t* __restrict__ Bt,
    const float* __restrict__ bias, void* __restrict__ Cv,
    int M, int N, int K, int nx) {
  __shared__ uint16_t As[2][256 * 64];
  __shared__ uint16_t Bs[2][256 * 64];
  int nwg = gridDim.x, bid = blockIdx.x;
  int cpx = nwg >> 3;
  int swzb = (bid & 7) * cpx + (bid >> 3);
  int ntile = nwg / NSPLIT;
  int sp = swzb / ntile, rr0 = swzb % ntile;
  int n0 = (rr0 % nx) * 256, m0 = (rr0 / nx) * 256;
  int Klen = K / NSPLIT;
  int tid = threadIdx.x, w = tid >> 6, l = tid & 63;
  int wr = w >> 2, wc = w & 3;
  int lr = l & 15, lg = l >> 4;
  f32x4 acc[8][4] = {};
  const uint16_t* Ab = A + (size_t)m0 * K + sp * Klen;
  const uint16_t* Bb = Bt + (size_t)n0 * K + sp * Klen;
  int colb = (((l & 7) ^ (l >> 3)) << 4);  // inverse-swizzled source col
  int srl = l >> 3;                        // lane sub-row 0..7

  auto stageH = [&](int buf, int k0, int h) {
    const uint16_t* base = (h < 2) ? Ab : Bb;
    uint16_t* lds = (h < 2) ? &As[buf][0] : &Bs[buf][0];
    int hh = (h & 1) * 128;
#pragma unroll
    for (int j = 0; j < 2; j++) {
      int rr = hh + j * 64 + w * 8;  // wave-uniform row base
      gload_lds16((const uint8_t*)(base + (size_t)(rr + srl) * K + k0) + colb,
                  &lds[rr * 64]);
    }
  };

#pragma unroll
  for (int h = 0; h < 4; h++) stageH(0, 0, h);
  asm volatile("s_waitcnt vmcnt(0)" ::: "memory");
  __builtin_amdgcn_s_barrier();

  int nt = Klen >> 6;
  int swr = (lr & 7) << 4;
  for (int t = 0; t < nt; t++) {
    int buf = t & 1;
    bf16x8 bfr[2][4];
#pragma unroll
    for (int ks = 0; ks < 2; ks++) {
#pragma unroll
      for (int mq = 0; mq < 2; mq++) {
        const int ph = ks * 2 + mq;
        int off = ((ks << 6) | (lg << 4)) ^ swr;
        bf16x8 af[4];
#pragma unroll
        for (int m = 0; m < 4; m++) {
          int row = wr * 128 + (mq * 4 + m) * 16 + lr;
          af[m] = *(const bf16x8*)((const uint8_t*)&As[buf][row * 64] + off);
        }
        if (mq == 0) {
#pragma unroll
          for (int n = 0; n < 4; n++) {
            int row = wc * 64 + n * 16 + lr;
            bfr[ks][n] = *(const bf16x8*)((const uint8_t*)&Bs[buf][row * 64] + off);
          }
        }
        if (t + 1 < nt) {
          if (ph == 0) { stageH(buf ^ 1, (t + 1) * 64, 0); stageH(buf ^ 1, (t + 1) * 64, 1); }
          if (ph == 1) { stageH(buf ^ 1, (t + 1) * 64, 2); stageH(buf ^ 1, (t + 1) * 64, 3); }
        }
        __builtin_amdgcn_s_barrier();
        asm volatile("s_waitcnt lgkmcnt(0)" ::: "memory");
        __builtin_amdgcn_sched_barrier(0);
        __builtin_amdgcn_s_setprio(1);
#pragma unroll
        for (int m = 0; m < 4; m++)
#pragma unroll
          for (int n = 0; n < 4; n++)
            acc[mq * 4 + m][n] = __builtin_amdgcn_mfma_f32_16x16x32_bf16(
                af[m], bfr[ks][n], acc[mq * 4 + m][n], 0, 0, 0);
        __builtin_amdgcn_s_setprio(0);
        if (ph == 3) asm volatile("s_waitcnt vmcnt(0)" ::: "memory");  // t+1 loads done
        __builtin_amdgcn_s_barrier();
      }
    }
  }

#pragma unroll
  for (int m = 0; m < 8; m++) {
    int row = m0 + wr * 128 + m * 16 + lg * 4;
#pragma unroll
    for (int n = 0; n < 4; n++) {
      int col = n0 + wc * 64 + n * 16 + lr;
      float bv = (NSPLIT == 1 || sp == 0) ? bias[col] : 0.f;
#pragma unroll
      for (int j = 0; j < 4; j++) {
        float v = acc[m][n][j] + bv;
        if (MODE == 2) v = fmaxf(v, 0.f);
        size_t idx = (size_t)sp * M * N + (size_t)(row + j) * N + col;
        if (MODE == 0) ((float*)Cv)[idx] = v;
        else           ((uint16_t*)Cv)[idx] = f2b(v);
      }
    }
  }
}

// --------------------------------------------------------------- fused attention
// (round-11/12 proven: 512 blocks, 4 waves, 2 Q-frags/wave, 16x16 MFMA,
// KVBLK=128 double-buffered, XOR-swizzle, no-max softmax, deferred denominator)
__global__ __launch_bounds__(256, 2) void attn_fused(
    const uint16_t* __restrict__ qkv, const uint16_t* __restrict__ Vt,
    uint16_t* __restrict__ outb) {
  constexpr int LQ = 3072;
  constexpr float SC = 0.18033688f;  // 0.125 * log2(e)
  int L = blockIdx.x;
  int qb = (L >> 3) & 15;
  int bh = (L & 7) + 8 * (L >> 7);
  int b = bh >> 4, h = bh & 15;
  int w = threadIdx.x >> 6, l = threadIdx.x & 63;
  int lr = l & 15, lg = l >> 4;
  int qbase = qb * 128 + w * 32;

  __shared__ uint16_t Kbuf[2][2][64 * 64];  // [dbuf][sub][key-row][d]
  __shared__ uint16_t Vbuf[2][2][64 * 64];  // [dbuf][sub][d-row][key]
  __shared__ uint16_t Plds[4][2][16 * 64];  // per-wave, per-qfrag P tiles
  uint16_t* PwA = &Plds[w][0][0];
  uint16_t* PwB = &Plds[w][1][0];

  const uint16_t* qrowA = qkv + (size_t)(b * 2048 + qbase + lr) * LQ + h * 64;
  const uint16_t* qrowB = qrowA + (size_t)16 * LQ;
  bf16x8 qA0 = scale8(*(const bf16x8*)(qrowA + lg * 8), SC);
  bf16x8 qA1 = scale8(*(const bf16x8*)(qrowA + 32 + lg * 8), SC);
  bf16x8 qB0 = scale8(*(const bf16x8*)(qrowB + lg * 8), SC);
  bf16x8 qB1 = scale8(*(const bf16x8*)(qrowB + 32 + lg * 8), SC);

  float rsA = 0.f, rsB = 0.f;
  f32x4 oA[4] = {}, oB[4] = {};

  const uint8_t* kq = (const uint8_t*)qkv;
  const uint8_t* vq = (const uint8_t*)Vt;
  int colb = (((l & 7) ^ ((l >> 3) & 7)) << 4);
  int Rl = w * 16 + (l >> 3);

  auto stageKV = [&](int buf, int kb) {
#pragma unroll
    for (int s2 = 0; s2 < 2; s2++) {
#pragma unroll
      for (int c2 = 0; c2 < 2; c2++) {
        int R = Rl + c2 * 8;
        const uint8_t* ks =
            kq + ((size_t)(b * 2048 + kb + s2 * 64 + R) * LQ + 1024 + h * 64) * 2 + colb;
        gload_lds16(ks, &Kbuf[buf][s2][(w * 16 + c2 * 8) * 64]);
        const uint8_t* vs =
            vq + ((size_t)(bh * 64 + R) * 2048 + kb + s2 * 64) * 2 + colb;
        gload_lds16(vs, &Vbuf[buf][s2][(w * 16 + c2 * 8) * 64]);
      }
    }
  };

  stageKV(0, 0);
  __syncthreads();

  int swz = (lr & 7) << 4;
  for (int kb = 0; kb < 2048; kb += 128) {
    int cur = (kb >> 7) & 1;
    if (kb + 128 < 2048) stageKV(cur ^ 1, kb + 128);

#pragma unroll
    for (int s2 = 0; s2 < 2; s2++) {
      const uint8_t* Kb = (const uint8_t*)Kbuf[cur][s2];
      const uint8_t* Vb = (const uint8_t*)Vbuf[cur][s2];
      f32x4 sA[4], sB[4];
      __builtin_amdgcn_s_setprio(1);
#pragma unroll
      for (int t = 0; t < 4; t++) {
        const uint8_t* rb = Kb + (16 * t + lr) * 128;
        bf16x8 k0 = *(const bf16x8*)(rb + ((lg << 4) ^ swz));
        bf16x8 k1 = *(const bf16x8*)(rb + ((64 | (lg << 4)) ^ swz));
        f32x4 zA = {};
        zA = __builtin_amdgcn_mfma_f32_16x16x32_bf16(k0, qA0, zA, 0, 0, 0);
        zA = __builtin_amdgcn_mfma_f32_16x16x32_bf16(k1, qA1, zA, 0, 0, 0);
        sA[t] = zA;
        f32x4 zB = {};
        zB = __builtin_amdgcn_mfma_f32_16x16x32_bf16(k0, qB0, zB, 0, 0, 0);
        zB = __builtin_amdgcn_mfma_f32_16x16x32_bf16(k1, qB1, zB, 0, 0, 0);
        sB[t] = zB;
      }
      __builtin_amdgcn_s_setprio(0);
#pragma unroll
      for (int t = 0; t < 4; t++) {
        float a0 = __builtin_amdgcn_exp2f(sA[t][0]);
        float a1 = __builtin_amdgcn_exp2f(sA[t][1]);
        float a2 = __builtin_amdgcn_exp2f(sA[t][2]);
        float a3 = __builtin_amdgcn_exp2f(sA[t][3]);
        rsA += (a0 + a1) + (a2 + a3);
        uint2 pa;
        pa.x = pkbf2(a0, a1);
        pa.y = pkbf2(a2, a3);
        *(uint2*)((uint8_t*)PwA + lr * 128 + ((t * 32 + lg * 8) ^ swz)) = pa;
        float b0 = __builtin_amdgcn_exp2f(sB[t][0]);
        float b1 = __builtin_amdgcn_exp2f(sB[t][1]);
        float b2 = __builtin_amdgcn_exp2f(sB[t][2]);
        float b3 = __builtin_amdgcn_exp2f(sB[t][3]);
        rsB += (b0 + b1) + (b2 + b3);
        uint2 pb;
        pb.x = pkbf2(b0, b1);
        pb.y = pkbf2(b2, b3);
        *(uint2*)((uint8_t*)PwB + lr * 128 + ((t * 32 + lg * 8) ^ swz)) = pb;
      }
      __builtin_amdgcn_wave_barrier();  // keep ds_reads after ds_writes (same-wave order)
      bf16x8 pA0 = *(const bf16x8*)((const uint8_t*)PwA + lr * 128 + ((lg << 4) ^ swz));
      bf16x8 pA1 = *(const bf16x8*)((const uint8_t*)PwA + lr * 128 + ((64 | (lg << 4)) ^ swz));
      bf16x8 pB0 = *(const bf16x8*)((const uint8_t*)PwB + lr * 128 + ((lg << 4) ^ swz));
      bf16x8 pB1 = *(const bf16x8*)((const uint8_t*)PwB + lr * 128 + ((64 | (lg << 4)) ^ swz));
      __builtin_amdgcn_s_setprio(1);
#pragma unroll
      for (int t = 0; t < 4; t++) {
        const uint8_t* rb = Vb + (16 * t + lr) * 128;
        bf16x8 v0 = *(const bf16x8*)(rb + ((lg << 4) ^ swz));
        bf16x8 v1 = *(const bf16x8*)(rb + ((64 | (lg << 4)) ^ swz));
        oA[t] = __builtin_amdgcn_mfma_f32_16x16x32_bf16(v0, pA0, oA[t], 0, 0, 0);
        oA[t] = __builtin_amdgcn_mfma_f32_16x16x32_bf16(v1, pA1, oA[t], 0, 0, 0);
        oB[t] = __builtin_amdgcn_mfma_f32_16x16x32_bf16(v0, pB0, oB[t], 0, 0, 0);
        oB[t] = __builtin_amdgcn_mfma_f32_16x16x32_bf16(v1, pB1, oB[t], 0, 0, 0);
      }
      __builtin_amdgcn_s_setprio(0);
      if (s2 == 0) __builtin_amdgcn_wave_barrier();  // P reuse: reads before next writes
    }
    __syncthreads();  // drains stage vmcnt + all waves done reading cur
  }
  rsA += __shfl_xor(rsA, 16);
  rsA += __shfl_xor(rsA, 32);
  rsB += __shfl_xor(rsB, 16);
  rsB += __shfl_xor(rsB, 32);
  float invA = 1.f / rsA, invB = 1.f / rsB;
  uint16_t* orowA = outb + (size_t)(b * 2048 + qbase + lr) * 1024 + h * 64;
  uint16_t* orowB = orowA + (size_t)16 * 1024;
#pragma unroll
  for (int t = 0; t < 4; t++) {
    uint2 ra;
    ra.x = pkbf2(oA[t][0] * invA, oA[t][1] * invA);
    ra.y = pkbf2(oA[t][2] * invA, oA[t][3] * invA);
    *(uint2*)(orowA + t * 16 + lg * 4) = ra;
    uint2 rb2;
    rb2.x = pkbf2(oB[t][0] * invB, oB[t][1] * invB);
    rb2.y = pkbf2(oB[t][2] * invB, oB[t][3] * invB);
    *(uint2*)(orowB + t * 16 + lg * 4) = rb2;
  }
}

// ------------------------------------------- LayerNorm(x + sum of NPART partials)
// XBF: xr is bf16. parts: NPART contiguous bf16 [4096][1024] partials.
template <int XBF, int WF32, int WB16, int NPART>
__global__ __launch_bounds__(256) void ln_res(
    const void* __restrict__ xr, const uint16_t* __restrict__ parts,
    const float* __restrict__ gam, const float* __restrict__ bet,
    float* __restrict__ of32, uint16_t* __restrict__ ob16) {
  int row = blockIdx.x, t = threadIdx.x;
  int w = t >> 6, l = t & 63;
  float v0, v1, v2, v3;
  if (XBF) {
    uint2 u = ((const uint2*)((const uint16_t*)xr + (size_t)row * 1024))[t];
    v0 = __uint_as_float((u.x & 0xffffu) << 16);
    v1 = __uint_as_float(u.x & 0xffff0000u);
    v2 = __uint_as_float((u.y & 0xffffu) << 16);
    v3 = __uint_as_float(u.y & 0xffff0000u);
  } else {
    float4 xv = ((const float4*)((const float*)xr + (size_t)row * 1024))[t];
    v0 = xv.x; v1 = xv.y; v2 = xv.z; v3 = xv.w;
  }
#pragma unroll
  for (int p = 0; p < NPART; p++) {
    uint2 u = ((const uint2*)(parts + (size_t)p * 4096 * 1024 +
                              (size_t)row * 1024))[t];
    v0 += __uint_as_float((u.x & 0xffffu) << 16);
    v1 += __uint_as_float(u.x & 0xffff0000u);
    v2 += __uint_as_float((u.y & 0xffffu) << 16);
    v3 += __uint_as_float(u.y & 0xffff0000u);
  }
  float s = v0 + v1 + v2 + v3;
  float sq = v0 * v0 + v1 * v1 + v2 * v2 + v3 * v3;
#pragma unroll
  for (int d = 1; d < 64; d <<= 1) {
    s += __shfl_xor(s, d);
    sq += __shfl_xor(sq, d);
  }
  __shared__ float red[8];
  if (l == 0) { red[w] = s; red[4 + w] = sq; }
  __syncthreads();
  s = red[0] + red[1] + red[2] + red[3];
  sq = red[4] + red[5] + red[6] + red[7];
  float mean = s * (1.f / 1024.f);
  float var = sq * (1.f / 1024.f) - mean * mean;
  float rstd = rsqrtf(var + 1e-5f);
  float4 gv = ((const float4*)gam)[t];
  float4 bv = ((const float4*)bet)[t];
  float y0 = (v0 - mean) * rstd * gv.x + bv.x;
  float y1 = (v1 - mean) * rstd * gv.y + bv.y;
  float y2 = (v2 - mean) * rstd * gv.z + bv.z;
  float y3 = (v3 - mean) * rstd * gv.w + bv.w;
  if (WF32) {
    float4 yv; yv.x = y0; yv.y = y1; yv.z = y2; yv.w = y3;
    ((float4*)(of32 + (size_t)row * 1024))[t] = yv;
  }
  if (WB16) {
    uint2 r;
    r.x = pkbf2(y0, y1);
    r.y = pkbf2(y2, y3);
    ((uint2*)(ob16 + (size_t)row * 1024))[t] = r;
  }
}

// ---------------------------------------------------------------- workspace map
static constexpr size_t OFF_XB    = 0;                          // 8 MB x_bf16 (live thru LN1)
static constexpr size_t OFF_WQKVT = (size_t)8 << 20;            // 6 MB [3072][1024]
static constexpr size_t OFF_WOT   = (size_t)14 << 20;           // 2 MB [1024][1024]
static constexpr size_t OFF_W1T   = (size_t)16 << 20;           // 8 MB [4096][1024]
static constexpr size_t OFF_W2T   = (size_t)24 << 20;           // 8 MB [1024][4096]
static constexpr size_t OFF_BIAS  = (size_t)32 << 20;           // 12 KB f32 (pad 64K)
static constexpr size_t OFF_QKV   = OFF_BIAS + ((size_t)64 << 10);  // 24 MB; +VT reused: H (32MB)
static constexpr size_t OFF_VT    = OFF_QKV + ((size_t)24 << 20);   // 8 MB [32][64][2048]
static constexpr size_t OFF_PROJ  = OFF_VT + ((size_t)8 << 20);     // 32 MB: 4x bf16 partials
static constexpr size_t OFF_LN1B  = OFF_PROJ + ((size_t)32 << 20);  // 8 MB bf16 trunk
static constexpr size_t OFF_ATTN  = OFF_LN1B + ((size_t)8 << 20);   // 8 MB attn out
// total ~120 MB

extern "C" void kernel_launch(void* const* d_in, const int* in_sizes, int n_in,
                              void* d_out, int out_size, void* d_ws, size_t ws_size,
                              hipStream_t stream) {
  const float* x   = (const float*)d_in[0];
  const float* Wq  = (const float*)d_in[1];
  const float* bq  = (const float*)d_in[2];
  const float* Wk  = (const float*)d_in[3];
  const float* bk  = (const float*)d_in[4];
  const float* Wv  = (const float*)d_in[5];
  const float* bv  = (const float*)d_in[6];
  const float* Wo  = (const float*)d_in[7];
  const float* bo  = (const float*)d_in[8];
  const float* W1  = (const float*)d_in[9];
  const float* b1  = (const float*)d_in[10];
  const float* W2  = (const float*)d_in[11];
  const float* b2  = (const float*)d_in[12];
  const float* g1  = (const float*)d_in[13];
  const float* be1 = (const float*)d_in[14];
  const float* g2  = (const float*)d_in[15];
  const float* be2 = (const float*)d_in[16];
  float* out = (float*)d_out;
  uint8_t* ws = (uint8_t*)d_ws;

  uint16_t* xb    = (uint16_t*)(ws + OFF_XB);
  uint16_t* wqkt  = (uint16_t*)(ws + OFF_WQKVT);
  uint16_t* wot   = (uint16_t*)(ws + OFF_WOT);
  uint16_t* w1t   = (uint16_t*)(ws + OFF_W1T);
  uint16_t* w2t   = (uint16_t*)(ws + OFF_W2T);
  float*    bqkv  = (float*)(ws + OFF_BIAS);
  uint16_t* qkvb  = (uint16_t*)(ws + OFF_QKV);
  uint16_t* vt    = (uint16_t*)(ws + OFF_VT);
  uint16_t* proj  = (uint16_t*)(ws + OFF_PROJ);   // up to 4x contiguous partials
  uint16_t* ln1b  = (uint16_t*)(ws + OFF_LN1B);
  uint16_t* attnb = (uint16_t*)(ws + OFF_ATTN);
  uint16_t* hbuf  = (uint16_t*)(ws + OFF_QKV);  // alias: qkv+vt dead after attention

  // 1. merged prep: cast x, all weight transposes, bias concat (one dispatch)
  prep_all<<<16396, 256, 0, stream>>>(x, xb, Wq, Wk, Wv, wqkt, Wo, wot,
                                      W1, w1t, W2, w2t, bq, bk, bv, bqkv);
  // 2. fused QKV projection; V columns written directly transposed to vt
  gemm_bt<1, 1, 32, 1><<<768, 256, 0, stream>>>(xb, wqkt, bqkv, qkvb, vt,
                                                4096, 3072, 1024, 24);
  // 3. fused attention (512 blocks, 16x16 MFMA, KVBLK=128)
  attn_fused<<<512, 256, 0, stream>>>(qkvb, vt, attnb);
  // 4. output projection: 128x128 split-K x2, BK=64 (512 blocks, 2/CU)
  gemm_bt<1, 2, 64, 0><<<512, 256, 0, stream>>>(attnb, wot, bo, proj, nullptr,
                                                4096, 1024, 1024, 8);
  // 5. LN1(xb + p0 + p1) -> bf16 trunk only
  ln_res<1, 0, 1, 2><<<4096, 256, 0, stream>>>(xb, proj, g1, be1,
                                               nullptr, ln1b);
  // 6. MLP1 + relu -> bf16, 256x256 phase-split (256 blocks, 1/CU, nt=16)
  gemm256<2, 1><<<256, 512, 0, stream>>>(ln1b, w1t, b1, hbuf,
                                         4096, 4096, 1024, 16);
  // 7. MLP2: 256x256 phase-split, split-K x4 (256 blocks, nt=16)
  gemm256<1, 4><<<256, 512, 0, stream>>>(hbuf, w2t, b2, proj,
                                         4096, 1024, 4096, 4);
  // 8. LN2(ln1b + p0..p3) -> d_out fp32
  ln_res<1, 1, 0, 4><<<4096, 256, 0, stream>>>(ln1b, proj, g2, be2,
                                               out, nullptr);
}

// Round 23
// 206.406 us; speedup vs baseline: 1.0445x; 1.0034x over previous
//
#include <hip/hip_runtime.h>
#include <hip/hip_bf16.h>
#include <cstdint>

#define DEV __device__ __forceinline__

typedef __attribute__((ext_vector_type(8))) __bf16 bf16x8;
typedef __attribute__((ext_vector_type(4))) float f32x4;

// fp32 -> bf16 via HW cvt (single v_cvt instruction)
DEV uint16_t f2b(float f) {
  __hip_bfloat16 h = __float2bfloat16(f);
  return *(uint16_t*)&h;
}
// pack two floats into a bf16x2 word
DEV uint32_t pkbf2(float a, float b) {
  return (uint32_t)f2b(a) | ((uint32_t)f2b(b) << 16);
}
// pack four floats into 4x bf16 (uint64)
DEV uint64_t pkbf4(float a, float b, float c, float d) {
  return (uint64_t)pkbf2(a, b) | ((uint64_t)pkbf2(c, d) << 32);
}

// async global->LDS, 16B per lane. LDS base must be wave-uniform; HW writes
// base + lane*16. Global source address is per-lane.
DEV void gload_lds16(const void* g, void* l) {
  __builtin_amdgcn_global_load_lds(
      (const __attribute__((address_space(1))) void*)g,
      (__attribute__((address_space(3))) void*)l, 16, 0, 0);
}

// scale a bf16x8 by a constant (via fp32, RNE back to bf16)
DEV bf16x8 scale8(bf16x8 v, float sc) {
  union { bf16x8 b; uint16_t u[8]; } in, out;
  in.b = v;
#pragma unroll
  for (int i = 0; i < 8; i++) {
    float x = __uint_as_float(((uint32_t)in.u[i]) << 16);
    out.u[i] = f2b(x * sc);
  }
  return out.b;
}

// ------------------------------------------------------- merged prep kernel
// One dispatch: cast_x, transpose(Wq|Wk|Wv), transpose(Wo), transpose(W1),
// transpose(W2), concat3(biases). Vectorized global I/O: float4 loads,
// uint64 (4x bf16) stores. blocks: [0,4096) cast | [4096,7168) w3 |
// [7168,8192) Wo | [8192,12288) W1 | [12288,16384) W2 | [16384,16396) concat
__global__ __launch_bounds__(256) void prep_all(
    const float* __restrict__ x, uint16_t* __restrict__ xb,
    const float* __restrict__ Wq, const float* __restrict__ Wk,
    const float* __restrict__ Wv, uint16_t* __restrict__ wqkt,
    const float* __restrict__ Wo, uint16_t* __restrict__ wot,
    const float* __restrict__ W1, uint16_t* __restrict__ w1t,
    const float* __restrict__ W2, uint16_t* __restrict__ w2t,
    const float* __restrict__ bq, const float* __restrict__ bk,
    const float* __restrict__ bv, float* __restrict__ bqkv) {
  __shared__ float t[32][33];
  int bid = blockIdx.x, tid = threadIdx.x;
  if (bid < 4096) {               // ---- cast x -> bf16
    int i = bid * 256 + tid;
    float4 v = ((const float4*)x)[i];
    ((uint64_t*)xb)[i] = pkbf4(v.x, v.y, v.z, v.w);
    return;
  }
  if (bid >= 16384) {             // ---- bias concat
    int i = (bid - 16384) * 256 + tid;
    if (i < 3072)
      bqkv[i] = i < 1024 ? bq[i] : (i < 2048 ? bk[i - 1024] : bv[i - 2048]);
    return;
  }
  // ---- weight transpose fp32[R][C] -> bf16[C][R], 32x32 tile
  const float* src;
  uint16_t* dst;
  int R, C, bx, by;
  if (bid < 8192) {
    int local = bid - 4096;
    if (local < 3072) {           // Wq|Wk|Wv (1024x1024 each)
      int z = local >> 10, rem = local & 1023;
      src = z == 0 ? Wq : (z == 1 ? Wk : Wv);
      dst = wqkt + (size_t)z * 1024 * 1024;
      R = 1024; C = 1024; bx = rem & 31; by = rem >> 5;
    } else {                      // Wo
      int rem = local - 3072;
      src = Wo; dst = wot; R = 1024; C = 1024; bx = rem & 31; by = rem >> 5;
    }
  } else if (bid < 12288) {       // W1: [1024][4096] -> [4096][1024]
    int rem = bid - 8192;
    src = W1; dst = w1t; R = 1024; C = 4096; bx = rem & 127; by = rem >> 7;
  } else {                        // W2: [4096][1024] -> [1024][4096]
    int rem = bid - 12288;
    src = W2; dst = w2t; R = 4096; C = 1024; bx = rem & 31; by = rem >> 5;
  }
  int c0 = bx * 32, r0 = by * 32;
  // load: float4 per thread (16B/lane)
  int lrow = tid >> 3, lc = (tid & 7) * 4;
  float4 v = *(const float4*)&src[(size_t)(r0 + lrow) * C + c0 + lc];
  t[lrow][lc] = v.x; t[lrow][lc + 1] = v.y;
  t[lrow][lc + 2] = v.z; t[lrow][lc + 3] = v.w;
  __syncthreads();
  // store: 4x bf16 per thread along R (8B/lane)
  int cr = tid >> 3, rq = (tid & 7) * 4;
  uint64_t r = pkbf4(t[rq][cr], t[rq + 1][cr], t[rq + 2][cr], t[rq + 3][cr]);
  *(uint64_t*)&dst[(size_t)(c0 + cr) * R + r0 + rq] = r;
}

// ------------------------------------------------------------------------- GEMM
// 128x128 tile, 4 waves, BK=32 linear / BK=64 swizzled, 2-phase pipeline.
// NSPLIT: K split; split sp writes partial sp at Cv + sp*M*N (bf16 for MODE=1).
// QKV=1: N=3072 fused projection; column tiles >= 2048 are the V head-matrix
// and are written TRANSPOSED to vt[bh][d][s] (4 consecutive s per lane ->
// single packed uint64 store; 64B vt lines fully covered within one block).
// MODE: 0 = fp32 out, 1 = bf16 out, 2 = bf16 out + relu
template <int MODE, int NSPLIT, int BK, int QKV>
__global__ __launch_bounds__(256) void gemm_bt(
    const uint16_t* __restrict__ A, const uint16_t* __restrict__ Bt,
    const float* __restrict__ bias, void* __restrict__ Cv,
    uint16_t* __restrict__ vt, int M, int N, int K, int nx) {
  __shared__ uint16_t As[2][128 * BK];
  __shared__ uint16_t Bs[2][128 * BK];
  int nwg = gridDim.x, bid = blockIdx.x;
  int cpx = nwg >> 3;
  int swzb = (bid & 7) * cpx + (bid >> 3);  // XCD (bid&7) owns contiguous chunk
  int ntile = nwg / NSPLIT;
  int sp = swzb / ntile, r = swzb % ntile;
  int n0 = (r % nx) * 128, m0 = (r / nx) * 128;
  int Klen = K / NSPLIT;
  int tid = threadIdx.x, w = tid >> 6, l = tid & 63;
  int wr = w >> 1, wc = w & 1;
  int lr = l & 15, lg = l >> 4, lk8 = lg * 8;
  f32x4 acc[4][4] = {};
  const uint16_t* Ab = A + (size_t)m0 * K + sp * Klen;
  const uint16_t* Bb = Bt + (size_t)n0 * K + sp * Klen;

  auto stage = [&](int buf, int k0) {
    if (BK == 32) {
#pragma unroll
      for (int i = 0; i < 2; i++) {
        int c = 2 * w + i;             // 8 chunks of 16 rows
        int rr = c * 16 + (l >> 2);
        gload_lds16(Ab + (size_t)rr * K + k0 + (l & 3) * 8, &As[buf][c * 512]);
        gload_lds16(Bb + (size_t)rr * K + k0 + (l & 3) * 8, &Bs[buf][c * 512]);
      }
    } else {
      int colb = (((l & 7) ^ ((l >> 3) & 7)) << 4);  // inverse-swizzled source
#pragma unroll
      for (int i = 0; i < 4; i++) {
        int c = 4 * w + i;             // 16 chunks of 8 rows
        int rr = c * 8 + (l >> 3);
        gload_lds16((const uint8_t*)(Ab + (size_t)rr * K + k0) + colb,
                    &As[buf][c * 512]);
        gload_lds16((const uint8_t*)(Bb + (size_t)rr * K + k0) + colb,
                    &Bs[buf][c * 512]);
      }
    }
  };

  stage(0, 0);
  __syncthreads();

  for (int k0 = 0; k0 < Klen; k0 += BK) {
    int cur = (k0 / BK) & 1;
    if (k0 + BK < Klen) stage(cur ^ 1, k0 + BK);  // prefetch next tile
    if (BK == 32) {
      bf16x8 af[4], bf[4];
#pragma unroll
      for (int m = 0; m < 4; m++)
        af[m] = *(const bf16x8*)&As[cur][(wr * 64 + m * 16 + lr) * 32 + lk8];
#pragma unroll
      for (int n = 0; n < 4; n++)
        bf[n] = *(const bf16x8*)&Bs[cur][(wc * 64 + n * 16 + lr) * 32 + lk8];
#pragma unroll
      for (int m = 0; m < 4; m++)
#pragma unroll
        for (int n = 0; n < 4; n++)
          acc[m][n] = __builtin_amdgcn_mfma_f32_16x16x32_bf16(af[m], bf[n], acc[m][n], 0, 0, 0);
    } else {
      int sw = (lr & 7) << 4;
#pragma unroll
      for (int ks = 0; ks < 2; ks++) {
        int off = ((ks << 6) | (lg << 4)) ^ sw;  // swizzled read (matches source)
        bf16x8 af[4], bf[4];
#pragma unroll
        for (int m = 0; m < 4; m++)
          af[m] = *(const bf16x8*)((const uint8_t*)&As[cur][(wr * 64 + m * 16 + lr) * 64] + off);
#pragma unroll
        for (int n = 0; n < 4; n++)
          bf[n] = *(const bf16x8*)((const uint8_t*)&Bs[cur][(wc * 64 + n * 16 + lr) * 64] + off);
#pragma unroll
        for (int m = 0; m < 4; m++)
#pragma unroll
          for (int n = 0; n < 4; n++)
            acc[m][n] = __builtin_amdgcn_mfma_f32_16x16x32_bf16(af[m], bf[n], acc[m][n], 0, 0, 0);
      }
    }
    __syncthreads();  // drains prefetch vmcnt + all waves done with cur
  }

  int g4 = lg * 4;
  if (QKV && n0 >= 2048) {
    // V tile -> vt[bh][d][s], packed 4x bf16 along s
#pragma unroll
    for (int m = 0; m < 4; m++) {
      int row = m0 + wr * 64 + m * 16 + g4;   // s-range base (4 consecutive)
      int b_ = row >> 11, s_ = row & 2047;
#pragma unroll
      for (int n = 0; n < 4; n++) {
        int c = n0 - 2048 + wc * 64 + n * 16 + lr;   // h*64 + d
        float bv = bias[n0 + wc * 64 + n * 16 + lr];
        uint64_t pk = pkbf4(acc[m][n][0] + bv, acc[m][n][1] + bv,
                            acc[m][n][2] + bv, acc[m][n][3] + bv);
        size_t vidx = ((size_t)(b_ * 16 + (c >> 6))) * 131072 +
                      (size_t)(c & 63) * 2048 + s_;
        *(uint64_t*)&vt[vidx] = pk;
      }
    }
    return;
  }
#pragma unroll
  for (int m = 0; m < 4; m++) {
    int row = m0 + wr * 64 + m * 16 + g4;
#pragma unroll
    for (int n = 0; n < 4; n++) {
      int col = n0 + wc * 64 + n * 16 + lr;
      float bv = (NSPLIT == 1 || sp == 0) ? bias[col] : 0.f;
#pragma unroll
      for (int j = 0; j < 4; j++) {
        float v = acc[m][n][j] + bv;
        if (MODE == 2) v = fmaxf(v, 0.f);
        size_t idx = (size_t)sp * M * N + (size_t)(row + j) * N + col;
        if (MODE == 0) ((float*)Cv)[idx] = v;
        else           ((uint16_t*)Cv)[idx] = f2b(v);
      }
    }
  }
}

// ---------------------------------------------------- GEMM 256x256, phase-split
// (round-12 verified schedule) + NSPLIT split-K (contiguous bf16 partials).
// 512 thr = 8 waves, BK=64, 4 phases/K-tile, counted vmcnt drain at phase 3.
// NOTE: needs nt = Klen/64 >= 8 to amortize the prologue (round-16 lesson).
template <int MODE, int NSPLIT>
__global__ __launch_bounds__(512, 2) void gemm256(
    const uint16_t* __restrict__ A, const uint16_t* __restrict__ Bt,
    const float* __restrict__ bias, void* __restrict__ Cv,
    int M, int N, int K, int nx) {
  __shared__ uint16_t As[2][256 * 64];
  __shared__ uint16_t Bs[2][256 * 64];
  int nwg = gridDim.x, bid = blockIdx.x;
  int cpx = nwg >> 3;
  int swzb = (bid & 7) * cpx + (bid >> 3);
  int ntile = nwg / NSPLIT;
  int sp = swzb / ntile, rr0 = swzb % ntile;
  int n0 = (rr0 % nx) * 256, m0 = (rr0 / nx) * 256;
  int Klen = K / NSPLIT;
  int tid = threadIdx.x, w = tid >> 6, l = tid & 63;
  int wr = w >> 2, wc = w & 3;
  int lr = l & 15, lg = l >> 4;
  f32x4 acc[8][4] = {};
  const uint16_t* Ab = A + (size_t)m0 * K + sp * Klen;
  const uint16_t* Bb = Bt + (size_t)n0 * K + sp * Klen;
  int colb = (((l & 7) ^ (l >> 3)) << 4);  // inverse-swizzled source col
  int srl = l >> 3;                        // lane sub-row 0..7

  auto stageH = [&](int buf, int k0, int h) {
    const uint16_t* base = (h < 2) ? Ab : Bb;
    uint16_t* lds = (h < 2) ? &As[buf][0] : &Bs[buf][0];
    int hh = (h & 1) * 128;
#pragma unroll
    for (int j = 0; j < 2; j++) {
      int rr = hh + j * 64 + w * 8;  // wave-uniform row base
      gload_lds16((const uint8_t*)(base + (size_t)(rr + srl) * K + k0) + colb,
                  &lds[rr * 64]);
    }
  };

#pragma unroll
  for (int h = 0; h < 4; h++) stageH(0, 0, h);
  asm volatile("s_waitcnt vmcnt(0)" ::: "memory");
  __builtin_amdgcn_s_barrier();

  int nt = Klen >> 6;
  int swr = (lr & 7) << 4;
  for (int t = 0; t < nt; t++) {
    int buf = t & 1;
    bf16x8 bfr[2][4];
#pragma unroll
    for (int ks = 0; ks < 2; ks++) {
#pragma unroll
      for (int mq = 0; mq < 2; mq++) {
        const int ph = ks * 2 + mq;
        int off = ((ks << 6) | (lg << 4)) ^ swr;
        bf16x8 af[4];
#pragma unroll
        for (int m = 0; m < 4; m++) {
          int row = wr * 128 + (mq * 4 + m) * 16 + lr;
          af[m] = *(const bf16x8*)((const uint8_t*)&As[buf][row * 64] + off);
        }
        if (mq == 0) {
#pragma unroll
          for (int n = 0; n < 4; n++) {
            int row = wc * 64 + n * 16 + lr;
            bfr[ks][n] = *(const bf16x8*)((const uint8_t*)&Bs[buf][row * 64] + off);
          }
        }
        if (t + 1 < nt) {
          if (ph == 0) { stageH(buf ^ 1, (t + 1) * 64, 0); stageH(buf ^ 1, (t + 1) * 64, 1); }
          if (ph == 1) { stageH(buf ^ 1, (t + 1) * 64, 2); stageH(buf ^ 1, (t + 1) * 64, 3); }
        }
        __builtin_amdgcn_s_barrier();
        asm volatile("s_waitcnt lgkmcnt(0)" ::: "memory");
        __builtin_amdgcn_sched_barrier(0);
        __builtin_amdgcn_s_setprio(1);
#pragma unroll
        for (int m = 0; m < 4; m++)
#pragma unroll
          for (int n = 0; n < 4; n++)
            acc[mq * 4 + m][n] = __builtin_amdgcn_mfma_f32_16x16x32_bf16(
                af[m], bfr[ks][n], acc[mq * 4 + m][n], 0, 0, 0);
        __builtin_amdgcn_s_setprio(0);
        if (ph == 3) asm volatile("s_waitcnt vmcnt(0)" ::: "memory");  // t+1 loads done
        __builtin_amdgcn_s_barrier();
      }
    }
  }

#pragma unroll
  for (int m = 0; m < 8; m++) {
    int row = m0 + wr * 128 + m * 16 + lg * 4;
#pragma unroll
    for (int n = 0; n < 4; n++) {
      int col = n0 + wc * 64 + n * 16 + lr;
      float bv = (NSPLIT == 1 || sp == 0) ? bias[col] : 0.f;
#pragma unroll
      for (int j = 0; j < 4; j++) {
        float v = acc[m][n][j] + bv;
        if (MODE == 2) v = fmaxf(v, 0.f);
        size_t idx = (size_t)sp * M * N + (size_t)(row + j) * N + col;
        if (MODE == 0) ((float*)Cv)[idx] = v;
        else           ((uint16_t*)Cv)[idx] = f2b(v);
      }
    }
  }
}

// --------------------------------------------------------------- fused attention
// SINGLE-BUFFER variant (last untested cell of the {dbuf x occupancy} grid):
// KVBLK=128 kept (round-11 proven amortization) but no double buffer ->
// LDS 80->48 KB -> 3 blocks/CU (12 waves/CU, up from 8). Per tile: stage;
// __syncthreads (drain); compute both 64-key subrounds; __syncthreads (WAR).
// The exposed stage->drain latency is hidden by the other resident blocks'
// compute (m114 inter-block overlap) instead of intra-block prefetch.
__global__ __launch_bounds__(256, 3) void attn_fused(
    const uint16_t* __restrict__ qkv, const uint16_t* __restrict__ Vt,
    uint16_t* __restrict__ outb) {
  constexpr int LQ = 3072;
  constexpr float SC = 0.18033688f;  // 0.125 * log2(e)
  int L = blockIdx.x;
  int qb = (L >> 3) & 15;
  int bh = (L & 7) + 8 * (L >> 7);
  int b = bh >> 4, h = bh & 15;
  int w = threadIdx.x >> 6, l = threadIdx.x & 63;
  int lr = l & 15, lg = l >> 4;
  int qbase = qb * 128 + w * 32;

  __shared__ uint16_t Kbuf[2][64 * 64];     // [sub][key-row][d] (single buffer)
  __shared__ uint16_t Vbuf[2][64 * 64];     // [sub][d-row][key]
  __shared__ uint16_t Plds[4][2][16 * 64];  // per-wave, per-qfrag P tiles
  uint16_t* PwA = &Plds[w][0][0];
  uint16_t* PwB = &Plds[w][1][0];

  const uint16_t* qrowA = qkv + (size_t)(b * 2048 + qbase + lr) * LQ + h * 64;
  const uint16_t* qrowB = qrowA + (size_t)16 * LQ;
  bf16x8 qA0 = scale8(*(const bf16x8*)(qrowA + lg * 8), SC);
  bf16x8 qA1 = scale8(*(const bf16x8*)(qrowA + 32 + lg * 8), SC);
  bf16x8 qB0 = scale8(*(const bf16x8*)(qrowB + lg * 8), SC);
  bf16x8 qB1 = scale8(*(const bf16x8*)(qrowB + 32 + lg * 8), SC);

  float rsA = 0.f, rsB = 0.f;
  f32x4 oA[4] = {}, oB[4] = {};

  const uint8_t* kq = (const uint8_t*)qkv;
  const uint8_t* vq = (const uint8_t*)Vt;
  int colb = (((l & 7) ^ ((l >> 3) & 7)) << 4);
  int Rl = w * 16 + (l >> 3);

  auto stageKV = [&](int kb) {
#pragma unroll
    for (int s2 = 0; s2 < 2; s2++) {
#pragma unroll
      for (int c2 = 0; c2 < 2; c2++) {
        int R = Rl + c2 * 8;
        const uint8_t* ks =
            kq + ((size_t)(b * 2048 + kb + s2 * 64 + R) * LQ + 1024 + h * 64) * 2 + colb;
        gload_lds16(ks, &Kbuf[s2][(w * 16 + c2 * 8) * 64]);
        const uint8_t* vs =
            vq + ((size_t)(bh * 64 + R) * 2048 + kb + s2 * 64) * 2 + colb;
        gload_lds16(vs, &Vbuf[s2][(w * 16 + c2 * 8) * 64]);
      }
    }
  };

  int swz = (lr & 7) << 4;
  for (int kb = 0; kb < 2048; kb += 128) {
    stageKV(kb);
    __syncthreads();  // drains stage vmcnt; other resident blocks hide this

#pragma unroll
    for (int s2 = 0; s2 < 2; s2++) {
      const uint8_t* Kb = (const uint8_t*)Kbuf[s2];
      const uint8_t* Vb = (const uint8_t*)Vbuf[s2];
      f32x4 sA[4], sB[4];
      __builtin_amdgcn_s_setprio(1);
#pragma unroll
      for (int t = 0; t < 4; t++) {
        const uint8_t* rb = Kb + (16 * t + lr) * 128;
        bf16x8 k0 = *(const bf16x8*)(rb + ((lg << 4) ^ swz));
        bf16x8 k1 = *(const bf16x8*)(rb + ((64 | (lg << 4)) ^ swz));
        f32x4 zA = {};
        zA = __builtin_amdgcn_mfma_f32_16x16x32_bf16(k0, qA0, zA, 0, 0, 0);
        zA = __builtin_amdgcn_mfma_f32_16x16x32_bf16(k1, qA1, zA, 0, 0, 0);
        sA[t] = zA;
        f32x4 zB = {};
        zB = __builtin_amdgcn_mfma_f32_16x16x32_bf16(k0, qB0, zB, 0, 0, 0);
        zB = __builtin_amdgcn_mfma_f32_16x16x32_bf16(k1, qB1, zB, 0, 0, 0);
        sB[t] = zB;
      }
      __builtin_amdgcn_s_setprio(0);
#pragma unroll
      for (int t = 0; t < 4; t++) {
        float a0 = __builtin_amdgcn_exp2f(sA[t][0]);
        float a1 = __builtin_amdgcn_exp2f(sA[t][1]);
        float a2 = __builtin_amdgcn_exp2f(sA[t][2]);
        float a3 = __builtin_amdgcn_exp2f(sA[t][3]);
        rsA += (a0 + a1) + (a2 + a3);
        uint2 pa;
        pa.x = pkbf2(a0, a1);
        pa.y = pkbf2(a2, a3);
        *(uint2*)((uint8_t*)PwA + lr * 128 + ((t * 32 + lg * 8) ^ swz)) = pa;
        float b0 = __builtin_amdgcn_exp2f(sB[t][0]);
        float b1 = __builtin_amdgcn_exp2f(sB[t][1]);
        float b2 = __builtin_amdgcn_exp2f(sB[t][2]);
        float b3 = __builtin_amdgcn_exp2f(sB[t][3]);
        rsB += (b0 + b1) + (b2 + b3);
        uint2 pb;
        pb.x = pkbf2(b0, b1);
        pb.y = pkbf2(b2, b3);
        *(uint2*)((uint8_t*)PwB + lr * 128 + ((t * 32 + lg * 8) ^ swz)) = pb;
      }
      __builtin_amdgcn_wave_barrier();  // keep ds_reads after ds_writes (same-wave order)
      bf16x8 pA0 = *(const bf16x8*)((const uint8_t*)PwA + lr * 128 + ((lg << 4) ^ swz));
      bf16x8 pA1 = *(const bf16x8*)((const uint8_t*)PwA + lr * 128 + ((64 | (lg << 4)) ^ swz));
      bf16x8 pB0 = *(const bf16x8*)((const uint8_t*)PwB + lr * 128 + ((lg << 4) ^ swz));
      bf16x8 pB1 = *(const bf16x8*)((const uint8_t*)PwB + lr * 128 + ((64 | (lg << 4)) ^ swz));
      __builtin_amdgcn_s_setprio(1);
#pragma unroll
      for (int t = 0; t < 4; t++) {
        const uint8_t* rb = Vb + (16 * t + lr) * 128;
        bf16x8 v0 = *(const bf16x8*)(rb + ((lg << 4) ^ swz));
        bf16x8 v1 = *(const bf16x8*)(rb + ((64 | (lg << 4)) ^ swz));
        oA[t] = __builtin_amdgcn_mfma_f32_16x16x32_bf16(v0, pA0, oA[t], 0, 0, 0);
        oA[t] = __builtin_amdgcn_mfma_f32_16x16x32_bf16(v1, pA1, oA[t], 0, 0, 0);
        oB[t] = __builtin_amdgcn_mfma_f32_16x16x32_bf16(v0, pB0, oB[t], 0, 0, 0);
        oB[t] = __builtin_amdgcn_mfma_f32_16x16x32_bf16(v1, pB1, oB[t], 0, 0, 0);
      }
      __builtin_amdgcn_s_setprio(0);
      if (s2 == 0) __builtin_amdgcn_wave_barrier();  // P reuse: reads before next writes
    }
    __syncthreads();  // WAR: all waves done reading before next stage overwrites
  }
  rsA += __shfl_xor(rsA, 16);
  rsA += __shfl_xor(rsA, 32);
  rsB += __shfl_xor(rsB, 16);
  rsB += __shfl_xor(rsB, 32);
  float invA = 1.f / rsA, invB = 1.f / rsB;
  uint16_t* orowA = outb + (size_t)(b * 2048 + qbase + lr) * 1024 + h * 64;
  uint16_t* orowB = orowA + (size_t)16 * 1024;
#pragma unroll
  for (int t = 0; t < 4; t++) {
    uint2 ra;
    ra.x = pkbf2(oA[t][0] * invA, oA[t][1] * invA);
    ra.y = pkbf2(oA[t][2] * invA, oA[t][3] * invA);
    *(uint2*)(orowA + t * 16 + lg * 4) = ra;
    uint2 rb2;
    rb2.x = pkbf2(oB[t][0] * invB, oB[t][1] * invB);
    rb2.y = pkbf2(oB[t][2] * invB, oB[t][3] * invB);
    *(uint2*)(orowB + t * 16 + lg * 4) = rb2;
  }
}

// ------------------------------------------- LayerNorm(x + sum of NPART partials)
// XBF: xr is bf16. parts: NPART contiguous bf16 [4096][1024] partials.
template <int XBF, int WF32, int WB16, int NPART>
__global__ __launch_bounds__(256) void ln_res(
    const void* __restrict__ xr, const uint16_t* __restrict__ parts,
    const float* __restrict__ gam, const float* __restrict__ bet,
    float* __restrict__ of32, uint16_t* __restrict__ ob16) {
  int row = blockIdx.x, t = threadIdx.x;
  int w = t >> 6, l = t & 63;
  float v0, v1, v2, v3;
  if (XBF) {
    uint2 u = ((const uint2*)((const uint16_t*)xr + (size_t)row * 1024))[t];
    v0 = __uint_as_float((u.x & 0xffffu) << 16);
    v1 = __uint_as_float(u.x & 0xffff0000u);
    v2 = __uint_as_float((u.y & 0xffffu) << 16);
    v3 = __uint_as_float(u.y & 0xffff0000u);
  } else {
    float4 xv = ((const float4*)((const float*)xr + (size_t)row * 1024))[t];
    v0 = xv.x; v1 = xv.y; v2 = xv.z; v3 = xv.w;
  }
#pragma unroll
  for (int p = 0; p < NPART; p++) {
    uint2 u = ((const uint2*)(parts + (size_t)p * 4096 * 1024 +
                              (size_t)row * 1024))[t];
    v0 += __uint_as_float((u.x & 0xffffu) << 16);
    v1 += __uint_as_float(u.x & 0xffff0000u);
    v2 += __uint_as_float((u.y & 0xffffu) << 16);
    v3 += __uint_as_float(u.y & 0xffff0000u);
  }
  float s = v0 + v1 + v2 + v3;
  float sq = v0 * v0 + v1 * v1 + v2 * v2 + v3 * v3;
#pragma unroll
  for (int d = 1; d < 64; d <<= 1) {
    s += __shfl_xor(s, d);
    sq += __shfl_xor(sq, d);
  }
  __shared__ float red[8];
  if (l == 0) { red[w] = s; red[4 + w] = sq; }
  __syncthreads();
  s = red[0] + red[1] + red[2] + red[3];
  sq = red[4] + red[5] + red[6] + red[7];
  float mean = s * (1.f / 1024.f);
  float var = sq * (1.f / 1024.f) - mean * mean;
  float rstd = rsqrtf(var + 1e-5f);
  float4 gv = ((const float4*)gam)[t];
  float4 bv = ((const float4*)bet)[t];
  float y0 = (v0 - mean) * rstd * gv.x + bv.x;
  float y1 = (v1 - mean) * rstd * gv.y + bv.y;
  float y2 = (v2 - mean) * rstd * gv.z + bv.z;
  float y3 = (v3 - mean) * rstd * gv.w + bv.w;
  if (WF32) {
    float4 yv; yv.x = y0; yv.y = y1; yv.z = y2; yv.w = y3;
    ((float4*)(of32 + (size_t)row * 1024))[t] = yv;
  }
  if (WB16) {
    uint2 r;
    r.x = pkbf2(y0, y1);
    r.y = pkbf2(y2, y3);
    ((uint2*)(ob16 + (size_t)row * 1024))[t] = r;
  }
}

// ---------------------------------------------------------------- workspace map
static constexpr size_t OFF_XB    = 0;                          // 8 MB x_bf16 (live thru LN1)
static constexpr size_t OFF_WQKVT = (size_t)8 << 20;            // 6 MB [3072][1024]
static constexpr size_t OFF_WOT   = (size_t)14 << 20;           // 2 MB [1024][1024]
static constexpr size_t OFF_W1T   = (size_t)16 << 20;           // 8 MB [4096][1024]
static constexpr size_t OFF_W2T   = (size_t)24 << 20;           // 8 MB [1024][4096]
static constexpr size_t OFF_BIAS  = (size_t)32 << 20;           // 12 KB f32 (pad 64K)
static constexpr size_t OFF_QKV   = OFF_BIAS + ((size_t)64 << 10);  // 24 MB; +VT reused: H (32MB)
static constexpr size_t OFF_VT    = OFF_QKV + ((size_t)24 << 20);   // 8 MB [32][64][2048]
static constexpr size_t OFF_PROJ  = OFF_VT + ((size_t)8 << 20);     // 32 MB: 4x bf16 partials
static constexpr size_t OFF_LN1B  = OFF_PROJ + ((size_t)32 << 20);  // 8 MB bf16 trunk
static constexpr size_t OFF_ATTN  = OFF_LN1B + ((size_t)8 << 20);   // 8 MB attn out
// total ~120 MB

extern "C" void kernel_launch(void* const* d_in, const int* in_sizes, int n_in,
                              void* d_out, int out_size, void* d_ws, size_t ws_size,
                              hipStream_t stream) {
  const float* x   = (const float*)d_in[0];
  const float* Wq  = (const float*)d_in[1];
  const float* bq  = (const float*)d_in[2];
  const float* Wk  = (const float*)d_in[3];
  const float* bk  = (const float*)d_in[4];
  const float* Wv  = (const float*)d_in[5];
  const float* bv  = (const float*)d_in[6];
  const float* Wo  = (const float*)d_in[7];
  const float* bo  = (const float*)d_in[8];
  const float* W1  = (const float*)d_in[9];
  const float* b1  = (const float*)d_in[10];
  const float* W2  = (const float*)d_in[11];
  const float* b2  = (const float*)d_in[12];
  const float* g1  = (const float*)d_in[13];
  const float* be1 = (const float*)d_in[14];
  const float* g2  = (const float*)d_in[15];
  const float* be2 = (const float*)d_in[16];
  float* out = (float*)d_out;
  uint8_t* ws = (uint8_t*)d_ws;

  uint16_t* xb    = (uint16_t*)(ws + OFF_XB);
  uint16_t* wqkt  = (uint16_t*)(ws + OFF_WQKVT);
  uint16_t* wot   = (uint16_t*)(ws + OFF_WOT);
  uint16_t* w1t   = (uint16_t*)(ws + OFF_W1T);
  uint16_t* w2t   = (uint16_t*)(ws + OFF_W2T);
  float*    bqkv  = (float*)(ws + OFF_BIAS);
  uint16_t* qkvb  = (uint16_t*)(ws + OFF_QKV);
  uint16_t* vt    = (uint16_t*)(ws + OFF_VT);
  uint16_t* proj  = (uint16_t*)(ws + OFF_PROJ);   // up to 4x contiguous partials
  uint16_t* ln1b  = (uint16_t*)(ws + OFF_LN1B);
  uint16_t* attnb = (uint16_t*)(ws + OFF_ATTN);
  uint16_t* hbuf  = (uint16_t*)(ws + OFF_QKV);  // alias: qkv+vt dead after attention

  // 1. merged prep: cast x, all weight transposes, bias concat (one dispatch)
  prep_all<<<16396, 256, 0, stream>>>(x, xb, Wq, Wk, Wv, wqkt, Wo, wot,
                                      W1, w1t, W2, w2t, bq, bk, bv, bqkv);
  // 2. fused QKV projection; V columns written directly transposed to vt
  gemm_bt<1, 1, 32, 1><<<768, 256, 0, stream>>>(xb, wqkt, bqkv, qkvb, vt,
                                                4096, 3072, 1024, 24);
  // 3. fused attention (512 blocks, single-buffer KVBLK=128, 3 blocks/CU)
  attn_fused<<<512, 256, 0, stream>>>(qkvb, vt, attnb);
  // 4. output projection: 128x128 split-K x2, BK=64 (512 blocks, 2/CU)
  gemm_bt<1, 2, 64, 0><<<512, 256, 0, stream>>>(attnb, wot, bo, proj, nullptr,
                                                4096, 1024, 1024, 8);
  // 5. LN1(xb + p0 + p1) -> bf16 trunk only
  ln_res<1, 0, 1, 2><<<4096, 256, 0, stream>>>(xb, proj, g1, be1,
                                               nullptr, ln1b);
  // 6. MLP1 + relu -> bf16, 256x256 phase-split (256 blocks, 1/CU, nt=16)
  gemm256<2, 1><<<256, 512, 0, stream>>>(ln1b, w1t, b1, hbuf,
                                         4096, 4096, 1024, 16);
  // 7. MLP2: 256x256 phase-split, split-K x4 (256 blocks, nt=16)
  gemm256<1, 4><<<256, 512, 0, stream>>>(hbuf, w2t, b2, proj,
                                         4096, 1024, 4096, 4);
  // 8. LN2(ln1b + p0..p3) -> d_out fp32
  ln_res<1, 1, 0, 4><<<4096, 256, 0, stream>>>(ln1b, proj, g2, be2,
                                               out, nullptr);
}

// Round 24
// 206.276 us; speedup vs baseline: 1.0451x; 1.0006x over previous
//
#include <hip/hip_runtime.h>
#include <hip/hip_bf16.h>
#include <cstdint>

#define DEV __device__ __forceinline__

typedef __attribute__((ext_vector_type(8))) __bf16 bf16x8;
typedef __attribute__((ext_vector_type(4))) float f32x4;

// fp32 -> bf16 via HW cvt (single v_cvt instruction)
DEV uint16_t f2b(float f) {
  __hip_bfloat16 h = __float2bfloat16(f);
  return *(uint16_t*)&h;
}
// pack two floats into a bf16x2 word
DEV uint32_t pkbf2(float a, float b) {
  return (uint32_t)f2b(a) | ((uint32_t)f2b(b) << 16);
}
// pack four floats into 4x bf16 (uint64)
DEV uint64_t pkbf4(float a, float b, float c, float d) {
  return (uint64_t)pkbf2(a, b) | ((uint64_t)pkbf2(c, d) << 32);
}

// async global->LDS, 16B per lane. LDS base must be wave-uniform; HW writes
// base + lane*16. Global source address is per-lane.
DEV void gload_lds16(const void* g, void* l) {
  __builtin_amdgcn_global_load_lds(
      (const __attribute__((address_space(1))) void*)g,
      (__attribute__((address_space(3))) void*)l, 16, 0, 0);
}

// scale a bf16x8 by a constant (via fp32, RNE back to bf16)
DEV bf16x8 scale8(bf16x8 v, float sc) {
  union { bf16x8 b; uint16_t u[8]; } in, out;
  in.b = v;
#pragma unroll
  for (int i = 0; i < 8; i++) {
    float x = __uint_as_float(((uint32_t)in.u[i]) << 16);
    out.u[i] = f2b(x * sc);
  }
  return out.b;
}

// ------------------------------------------------------- merged prep kernel
// One dispatch: cast_x, transpose(Wq|Wk|Wv), transpose(Wo), transpose(W1),
// transpose(W2), concat3(biases). Vectorized global I/O: float4 loads,
// uint64 (4x bf16) stores. blocks: [0,4096) cast | [4096,7168) w3 |
// [7168,8192) Wo | [8192,12288) W1 | [12288,16384) W2 | [16384,16396) concat
__global__ __launch_bounds__(256) void prep_all(
    const float* __restrict__ x, uint16_t* __restrict__ xb,
    const float* __restrict__ Wq, const float* __restrict__ Wk,
    const float* __restrict__ Wv, uint16_t* __restrict__ wqkt,
    const float* __restrict__ Wo, uint16_t* __restrict__ wot,
    const float* __restrict__ W1, uint16_t* __restrict__ w1t,
    const float* __restrict__ W2, uint16_t* __restrict__ w2t,
    const float* __restrict__ bq, const float* __restrict__ bk,
    const float* __restrict__ bv, float* __restrict__ bqkv) {
  __shared__ float t[32][33];
  int bid = blockIdx.x, tid = threadIdx.x;
  if (bid < 4096) {               // ---- cast x -> bf16
    int i = bid * 256 + tid;
    float4 v = ((const float4*)x)[i];
    ((uint64_t*)xb)[i] = pkbf4(v.x, v.y, v.z, v.w);
    return;
  }
  if (bid >= 16384) {             // ---- bias concat
    int i = (bid - 16384) * 256 + tid;
    if (i < 3072)
      bqkv[i] = i < 1024 ? bq[i] : (i < 2048 ? bk[i - 1024] : bv[i - 2048]);
    return;
  }
  // ---- weight transpose fp32[R][C] -> bf16[C][R], 32x32 tile
  const float* src;
  uint16_t* dst;
  int R, C, bx, by;
  if (bid < 8192) {
    int local = bid - 4096;
    if (local < 3072) {           // Wq|Wk|Wv (1024x1024 each)
      int z = local >> 10, rem = local & 1023;
      src = z == 0 ? Wq : (z == 1 ? Wk : Wv);
      dst = wqkt + (size_t)z * 1024 * 1024;
      R = 1024; C = 1024; bx = rem & 31; by = rem >> 5;
    } else {                      // Wo
      int rem = local - 3072;
      src = Wo; dst = wot; R = 1024; C = 1024; bx = rem & 31; by = rem >> 5;
    }
  } else if (bid < 12288) {       // W1: [1024][4096] -> [4096][1024]
    int rem = bid - 8192;
    src = W1; dst = w1t; R = 1024; C = 4096; bx = rem & 127; by = rem >> 7;
  } else {                        // W2: [4096][1024] -> [1024][4096]
    int rem = bid - 12288;
    src = W2; dst = w2t; R = 4096; C = 1024; bx = rem & 31; by = rem >> 5;
  }
  int c0 = bx * 32, r0 = by * 32;
  // load: float4 per thread (16B/lane)
  int lrow = tid >> 3, lc = (tid & 7) * 4;
  float4 v = *(const float4*)&src[(size_t)(r0 + lrow) * C + c0 + lc];
  t[lrow][lc] = v.x; t[lrow][lc + 1] = v.y;
  t[lrow][lc + 2] = v.z; t[lrow][lc + 3] = v.w;
  __syncthreads();
  // store: 4x bf16 per thread along R (8B/lane)
  int cr = tid >> 3, rq = (tid & 7) * 4;
  uint64_t r = pkbf4(t[rq][cr], t[rq + 1][cr], t[rq + 2][cr], t[rq + 3][cr]);
  *(uint64_t*)&dst[(size_t)(c0 + cr) * R + r0 + rq] = r;
}

// ------------------------------------------------------------------------- GEMM
// 128x128 tile, 4 waves, BK=32 linear / BK=64 swizzled, 2-phase pipeline.
// NSPLIT: K split; split sp writes partial sp at Cv + sp*M*N (bf16 for MODE=1).
// QKV=1: N=3072 fused projection; column tiles >= 2048 are the V head-matrix
// and are written TRANSPOSED to vt[bh][d][s] (4 consecutive s per lane ->
// single packed uint64 store; 64B vt lines fully covered within one block).
// MODE: 0 = fp32 out, 1 = bf16 out, 2 = bf16 out + relu
template <int MODE, int NSPLIT, int BK, int QKV>
__global__ __launch_bounds__(256) void gemm_bt(
    const uint16_t* __restrict__ A, const uint16_t* __restrict__ Bt,
    const float* __restrict__ bias, void* __restrict__ Cv,
    uint16_t* __restrict__ vt, int M, int N, int K, int nx) {
  __shared__ uint16_t As[2][128 * BK];
  __shared__ uint16_t Bs[2][128 * BK];
  int nwg = gridDim.x, bid = blockIdx.x;
  int cpx = nwg >> 3;
  int swzb = (bid & 7) * cpx + (bid >> 3);  // XCD (bid&7) owns contiguous chunk
  int ntile = nwg / NSPLIT;
  int sp = swzb / ntile, r = swzb % ntile;
  int n0 = (r % nx) * 128, m0 = (r / nx) * 128;
  int Klen = K / NSPLIT;
  int tid = threadIdx.x, w = tid >> 6, l = tid & 63;
  int wr = w >> 1, wc = w & 1;
  int lr = l & 15, lg = l >> 4, lk8 = lg * 8;
  f32x4 acc[4][4] = {};
  const uint16_t* Ab = A + (size_t)m0 * K + sp * Klen;
  const uint16_t* Bb = Bt + (size_t)n0 * K + sp * Klen;

  auto stage = [&](int buf, int k0) {
    if (BK == 32) {
#pragma unroll
      for (int i = 0; i < 2; i++) {
        int c = 2 * w + i;             // 8 chunks of 16 rows
        int rr = c * 16 + (l >> 2);
        gload_lds16(Ab + (size_t)rr * K + k0 + (l & 3) * 8, &As[buf][c * 512]);
        gload_lds16(Bb + (size_t)rr * K + k0 + (l & 3) * 8, &Bs[buf][c * 512]);
      }
    } else {
      int colb = (((l & 7) ^ ((l >> 3) & 7)) << 4);  // inverse-swizzled source
#pragma unroll
      for (int i = 0; i < 4; i++) {
        int c = 4 * w + i;             // 16 chunks of 8 rows
        int rr = c * 8 + (l >> 3);
        gload_lds16((const uint8_t*)(Ab + (size_t)rr * K + k0) + colb,
                    &As[buf][c * 512]);
        gload_lds16((const uint8_t*)(Bb + (size_t)rr * K + k0) + colb,
                    &Bs[buf][c * 512]);
      }
    }
  };

  stage(0, 0);
  __syncthreads();

  for (int k0 = 0; k0 < Klen; k0 += BK) {
    int cur = (k0 / BK) & 1;
    if (k0 + BK < Klen) stage(cur ^ 1, k0 + BK);  // prefetch next tile
    if (BK == 32) {
      bf16x8 af[4], bf[4];
#pragma unroll
      for (int m = 0; m < 4; m++)
        af[m] = *(const bf16x8*)&As[cur][(wr * 64 + m * 16 + lr) * 32 + lk8];
#pragma unroll
      for (int n = 0; n < 4; n++)
        bf[n] = *(const bf16x8*)&Bs[cur][(wc * 64 + n * 16 + lr) * 32 + lk8];
#pragma unroll
      for (int m = 0; m < 4; m++)
#pragma unroll
        for (int n = 0; n < 4; n++)
          acc[m][n] = __builtin_amdgcn_mfma_f32_16x16x32_bf16(af[m], bf[n], acc[m][n], 0, 0, 0);
    } else {
      int sw = (lr & 7) << 4;
#pragma unroll
      for (int ks = 0; ks < 2; ks++) {
        int off = ((ks << 6) | (lg << 4)) ^ sw;  // swizzled read (matches source)
        bf16x8 af[4], bf[4];
#pragma unroll
        for (int m = 0; m < 4; m++)
          af[m] = *(const bf16x8*)((const uint8_t*)&As[cur][(wr * 64 + m * 16 + lr) * 64] + off);
#pragma unroll
        for (int n = 0; n < 4; n++)
          bf[n] = *(const bf16x8*)((const uint8_t*)&Bs[cur][(wc * 64 + n * 16 + lr) * 64] + off);
#pragma unroll
        for (int m = 0; m < 4; m++)
#pragma unroll
          for (int n = 0; n < 4; n++)
            acc[m][n] = __builtin_amdgcn_mfma_f32_16x16x32_bf16(af[m], bf[n], acc[m][n], 0, 0, 0);
      }
    }
    __syncthreads();  // drains prefetch vmcnt + all waves done with cur
  }

  int g4 = lg * 4;
  if (QKV && n0 >= 2048) {
    // V tile -> vt[bh][d][s], packed 4x bf16 along s
#pragma unroll
    for (int m = 0; m < 4; m++) {
      int row = m0 + wr * 64 + m * 16 + g4;   // s-range base (4 consecutive)
      int b_ = row >> 11, s_ = row & 2047;
#pragma unroll
      for (int n = 0; n < 4; n++) {
        int c = n0 - 2048 + wc * 64 + n * 16 + lr;   // h*64 + d
        float bv = bias[n0 + wc * 64 + n * 16 + lr];
        uint64_t pk = pkbf4(acc[m][n][0] + bv, acc[m][n][1] + bv,
                            acc[m][n][2] + bv, acc[m][n][3] + bv);
        size_t vidx = ((size_t)(b_ * 16 + (c >> 6))) * 131072 +
                      (size_t)(c & 63) * 2048 + s_;
        *(uint64_t*)&vt[vidx] = pk;
      }
    }
    return;
  }
#pragma unroll
  for (int m = 0; m < 4; m++) {
    int row = m0 + wr * 64 + m * 16 + g4;
#pragma unroll
    for (int n = 0; n < 4; n++) {
      int col = n0 + wc * 64 + n * 16 + lr;
      float bv = (NSPLIT == 1 || sp == 0) ? bias[col] : 0.f;
#pragma unroll
      for (int j = 0; j < 4; j++) {
        float v = acc[m][n][j] + bv;
        if (MODE == 2) v = fmaxf(v, 0.f);
        size_t idx = (size_t)sp * M * N + (size_t)(row + j) * N + col;
        if (MODE == 0) ((float*)Cv)[idx] = v;
        else           ((uint16_t*)Cv)[idx] = f2b(v);
      }
    }
  }
}

// ---------------------------------------------------- GEMM 256x256, phase-split
// (round-12 verified schedule) + NSPLIT split-K (contiguous bf16 partials).
// 512 thr = 8 waves, BK=64, 4 phases/K-tile, counted vmcnt drain at phase 3.
// NOTE: needs nt = Klen/64 >= 8 to amortize the prologue (round-16 lesson).
template <int MODE, int NSPLIT>
__global__ __launch_bounds__(512, 2) void gemm256(
    const uint16_t* __restrict__ A, const uint16_t* __restrict__ Bt,
    const float* __restrict__ bias, void* __restrict__ Cv,
    int M, int N, int K, int nx) {
  __shared__ uint16_t As[2][256 * 64];
  __shared__ uint16_t Bs[2][256 * 64];
  int nwg = gridDim.x, bid = blockIdx.x;
  int cpx = nwg >> 3;
  int swzb = (bid & 7) * cpx + (bid >> 3);
  int ntile = nwg / NSPLIT;
  int sp = swzb / ntile, rr0 = swzb % ntile;
  int n0 = (rr0 % nx) * 256, m0 = (rr0 / nx) * 256;
  int Klen = K / NSPLIT;
  int tid = threadIdx.x, w = tid >> 6, l = tid & 63;
  int wr = w >> 2, wc = w & 3;
  int lr = l & 15, lg = l >> 4;
  f32x4 acc[8][4] = {};
  const uint16_t* Ab = A + (size_t)m0 * K + sp * Klen;
  const uint16_t* Bb = Bt + (size_t)n0 * K + sp * Klen;
  int colb = (((l & 7) ^ (l >> 3)) << 4);  // inverse-swizzled source col
  int srl = l >> 3;                        // lane sub-row 0..7

  auto stageH = [&](int buf, int k0, int h) {
    const uint16_t* base = (h < 2) ? Ab : Bb;
    uint16_t* lds = (h < 2) ? &As[buf][0] : &Bs[buf][0];
    int hh = (h & 1) * 128;
#pragma unroll
    for (int j = 0; j < 2; j++) {
      int rr = hh + j * 64 + w * 8;  // wave-uniform row base
      gload_lds16((const uint8_t*)(base + (size_t)(rr + srl) * K + k0) + colb,
                  &lds[rr * 64]);
    }
  };

#pragma unroll
  for (int h = 0; h < 4; h++) stageH(0, 0, h);
  asm volatile("s_waitcnt vmcnt(0)" ::: "memory");
  __builtin_amdgcn_s_barrier();

  int nt = Klen >> 6;
  int swr = (lr & 7) << 4;
  for (int t = 0; t < nt; t++) {
    int buf = t & 1;
    bf16x8 bfr[2][4];
#pragma unroll
    for (int ks = 0; ks < 2; ks++) {
#pragma unroll
      for (int mq = 0; mq < 2; mq++) {
        const int ph = ks * 2 + mq;
        int off = ((ks << 6) | (lg << 4)) ^ swr;
        bf16x8 af[4];
#pragma unroll
        for (int m = 0; m < 4; m++) {
          int row = wr * 128 + (mq * 4 + m) * 16 + lr;
          af[m] = *(const bf16x8*)((const uint8_t*)&As[buf][row * 64] + off);
        }
        if (mq == 0) {
#pragma unroll
          for (int n = 0; n < 4; n++) {
            int row = wc * 64 + n * 16 + lr;
            bfr[ks][n] = *(const bf16x8*)((const uint8_t*)&Bs[buf][row * 64] + off);
          }
        }
        if (t + 1 < nt) {
          if (ph == 0) { stageH(buf ^ 1, (t + 1) * 64, 0); stageH(buf ^ 1, (t + 1) * 64, 1); }
          if (ph == 1) { stageH(buf ^ 1, (t + 1) * 64, 2); stageH(buf ^ 1, (t + 1) * 64, 3); }
        }
        __builtin_amdgcn_s_barrier();
        asm volatile("s_waitcnt lgkmcnt(0)" ::: "memory");
        __builtin_amdgcn_sched_barrier(0);
        __builtin_amdgcn_s_setprio(1);
#pragma unroll
        for (int m = 0; m < 4; m++)
#pragma unroll
          for (int n = 0; n < 4; n++)
            acc[mq * 4 + m][n] = __builtin_amdgcn_mfma_f32_16x16x32_bf16(
                af[m], bfr[ks][n], acc[mq * 4 + m][n], 0, 0, 0);
        __builtin_amdgcn_s_setprio(0);
        if (ph == 3) asm volatile("s_waitcnt vmcnt(0)" ::: "memory");  // t+1 loads done
        __builtin_amdgcn_s_barrier();
      }
    }
  }

#pragma unroll
  for (int m = 0; m < 8; m++) {
    int row = m0 + wr * 128 + m * 16 + lg * 4;
#pragma unroll
    for (int n = 0; n < 4; n++) {
      int col = n0 + wc * 64 + n * 16 + lr;
      float bv = (NSPLIT == 1 || sp == 0) ? bias[col] : 0.f;
#pragma unroll
      for (int j = 0; j < 4; j++) {
        float v = acc[m][n][j] + bv;
        if (MODE == 2) v = fmaxf(v, 0.f);
        size_t idx = (size_t)sp * M * N + (size_t)(row + j) * N + col;
        if (MODE == 0) ((float*)Cv)[idx] = v;
        else           ((uint16_t*)Cv)[idx] = f2b(v);
      }
    }
  }
}

// --------------------------------------------------------------- fused attention
// SINGLE-BUFFER variant: KVBLK=128, LDS 48 KB. Per tile: stage; __syncthreads
// (drain); compute both 64-key subrounds; __syncthreads (WAR). Exposed
// stage latency is hidden by the other resident block's compute (m114).
__global__ __launch_bounds__(256, 3) void attn_fused(
    const uint16_t* __restrict__ qkv, const uint16_t* __restrict__ Vt,
    uint16_t* __restrict__ outb) {
  constexpr int LQ = 3072;
  constexpr float SC = 0.18033688f;  // 0.125 * log2(e)
  int L = blockIdx.x;
  int qb = (L >> 3) & 15;
  int bh = (L & 7) + 8 * (L >> 7);
  int b = bh >> 4, h = bh & 15;
  int w = threadIdx.x >> 6, l = threadIdx.x & 63;
  int lr = l & 15, lg = l >> 4;
  int qbase = qb * 128 + w * 32;

  __shared__ uint16_t Kbuf[2][64 * 64];     // [sub][key-row][d] (single buffer)
  __shared__ uint16_t Vbuf[2][64 * 64];     // [sub][d-row][key]
  __shared__ uint16_t Plds[4][2][16 * 64];  // per-wave, per-qfrag P tiles
  uint16_t* PwA = &Plds[w][0][0];
  uint16_t* PwB = &Plds[w][1][0];

  const uint16_t* qrowA = qkv + (size_t)(b * 2048 + qbase + lr) * LQ + h * 64;
  const uint16_t* qrowB = qrowA + (size_t)16 * LQ;
  bf16x8 qA0 = scale8(*(const bf16x8*)(qrowA + lg * 8), SC);
  bf16x8 qA1 = scale8(*(const bf16x8*)(qrowA + 32 + lg * 8), SC);
  bf16x8 qB0 = scale8(*(const bf16x8*)(qrowB + lg * 8), SC);
  bf16x8 qB1 = scale8(*(const bf16x8*)(qrowB + 32 + lg * 8), SC);

  float rsA = 0.f, rsB = 0.f;
  f32x4 oA[4] = {}, oB[4] = {};

  const uint8_t* kq = (const uint8_t*)qkv;
  const uint8_t* vq = (const uint8_t*)Vt;
  int colb = (((l & 7) ^ ((l >> 3) & 7)) << 4);
  int Rl = w * 16 + (l >> 3);

  auto stageKV = [&](int kb) {
#pragma unroll
    for (int s2 = 0; s2 < 2; s2++) {
#pragma unroll
      for (int c2 = 0; c2 < 2; c2++) {
        int R = Rl + c2 * 8;
        const uint8_t* ks =
            kq + ((size_t)(b * 2048 + kb + s2 * 64 + R) * LQ + 1024 + h * 64) * 2 + colb;
        gload_lds16(ks, &Kbuf[s2][(w * 16 + c2 * 8) * 64]);
        const uint8_t* vs =
            vq + ((size_t)(bh * 64 + R) * 2048 + kb + s2 * 64) * 2 + colb;
        gload_lds16(vs, &Vbuf[s2][(w * 16 + c2 * 8) * 64]);
      }
    }
  };

  int swz = (lr & 7) << 4;
  for (int kb = 0; kb < 2048; kb += 128) {
    stageKV(kb);
    __syncthreads();  // drains stage vmcnt; other resident blocks hide this

#pragma unroll
    for (int s2 = 0; s2 < 2; s2++) {
      const uint8_t* Kb = (const uint8_t*)Kbuf[s2];
      const uint8_t* Vb = (const uint8_t*)Vbuf[s2];
      f32x4 sA[4], sB[4];
      __builtin_amdgcn_s_setprio(1);
#pragma unroll
      for (int t = 0; t < 4; t++) {
        const uint8_t* rb = Kb + (16 * t + lr) * 128;
        bf16x8 k0 = *(const bf16x8*)(rb + ((lg << 4) ^ swz));
        bf16x8 k1 = *(const bf16x8*)(rb + ((64 | (lg << 4)) ^ swz));
        f32x4 zA = {};
        zA = __builtin_amdgcn_mfma_f32_16x16x32_bf16(k0, qA0, zA, 0, 0, 0);
        zA = __builtin_amdgcn_mfma_f32_16x16x32_bf16(k1, qA1, zA, 0, 0, 0);
        sA[t] = zA;
        f32x4 zB = {};
        zB = __builtin_amdgcn_mfma_f32_16x16x32_bf16(k0, qB0, zB, 0, 0, 0);
        zB = __builtin_amdgcn_mfma_f32_16x16x32_bf16(k1, qB1, zB, 0, 0, 0);
        sB[t] = zB;
      }
      __builtin_amdgcn_s_setprio(0);
#pragma unroll
      for (int t = 0; t < 4; t++) {
        float a0 = __builtin_amdgcn_exp2f(sA[t][0]);
        float a1 = __builtin_amdgcn_exp2f(sA[t][1]);
        float a2 = __builtin_amdgcn_exp2f(sA[t][2]);
        float a3 = __builtin_amdgcn_exp2f(sA[t][3]);
        rsA += (a0 + a1) + (a2 + a3);
        uint2 pa;
        pa.x = pkbf2(a0, a1);
        pa.y = pkbf2(a2, a3);
        *(uint2*)((uint8_t*)PwA + lr * 128 + ((t * 32 + lg * 8) ^ swz)) = pa;
        float b0 = __builtin_amdgcn_exp2f(sB[t][0]);
        float b1 = __builtin_amdgcn_exp2f(sB[t][1]);
        float b2 = __builtin_amdgcn_exp2f(sB[t][2]);
        float b3 = __builtin_amdgcn_exp2f(sB[t][3]);
        rsB += (b0 + b1) + (b2 + b3);
        uint2 pb;
        pb.x = pkbf2(b0, b1);
        pb.y = pkbf2(b2, b3);
        *(uint2*)((uint8_t*)PwB + lr * 128 + ((t * 32 + lg * 8) ^ swz)) = pb;
      }
      __builtin_amdgcn_wave_barrier();  // keep ds_reads after ds_writes (same-wave order)
      bf16x8 pA0 = *(const bf16x8*)((const uint8_t*)PwA + lr * 128 + ((lg << 4) ^ swz));
      bf16x8 pA1 = *(const bf16x8*)((const uint8_t*)PwA + lr * 128 + ((64 | (lg << 4)) ^ swz));
      bf16x8 pB0 = *(const bf16x8*)((const uint8_t*)PwB + lr * 128 + ((lg << 4) ^ swz));
      bf16x8 pB1 = *(const bf16x8*)((const uint8_t*)PwB + lr * 128 + ((64 | (lg << 4)) ^ swz));
      __builtin_amdgcn_s_setprio(1);
#pragma unroll
      for (int t = 0; t < 4; t++) {
        const uint8_t* rb = Vb + (16 * t + lr) * 128;
        bf16x8 v0 = *(const bf16x8*)(rb + ((lg << 4) ^ swz));
        bf16x8 v1 = *(const bf16x8*)(rb + ((64 | (lg << 4)) ^ swz));
        oA[t] = __builtin_amdgcn_mfma_f32_16x16x32_bf16(v0, pA0, oA[t], 0, 0, 0);
        oA[t] = __builtin_amdgcn_mfma_f32_16x16x32_bf16(v1, pA1, oA[t], 0, 0, 0);
        oB[t] = __builtin_amdgcn_mfma_f32_16x16x32_bf16(v0, pB0, oB[t], 0, 0, 0);
        oB[t] = __builtin_amdgcn_mfma_f32_16x16x32_bf16(v1, pB1, oB[t], 0, 0, 0);
      }
      __builtin_amdgcn_s_setprio(0);
      if (s2 == 0) __builtin_amdgcn_wave_barrier();  // P reuse: reads before next writes
    }
    __syncthreads();  // WAR: all waves done reading before next stage overwrites
  }
  rsA += __shfl_xor(rsA, 16);
  rsA += __shfl_xor(rsA, 32);
  rsB += __shfl_xor(rsB, 16);
  rsB += __shfl_xor(rsB, 32);
  float invA = 1.f / rsA, invB = 1.f / rsB;
  uint16_t* orowA = outb + (size_t)(b * 2048 + qbase + lr) * 1024 + h * 64;
  uint16_t* orowB = orowA + (size_t)16 * 1024;
#pragma unroll
  for (int t = 0; t < 4; t++) {
    uint2 ra;
    ra.x = pkbf2(oA[t][0] * invA, oA[t][1] * invA);
    ra.y = pkbf2(oA[t][2] * invA, oA[t][3] * invA);
    *(uint2*)(orowA + t * 16 + lg * 4) = ra;
    uint2 rb2;
    rb2.x = pkbf2(oB[t][0] * invB, oB[t][1] * invB);
    rb2.y = pkbf2(oB[t][2] * invB, oB[t][3] * invB);
    *(uint2*)(orowB + t * 16 + lg * 4) = rb2;
  }
}

// ------------------------------------------- LayerNorm(x + sum of NPART partials)
// XBF: xr is bf16. parts: NPART contiguous bf16 [4096][1024] partials.
template <int XBF, int WF32, int WB16, int NPART>
__global__ __launch_bounds__(256) void ln_res(
    const void* __restrict__ xr, const uint16_t* __restrict__ parts,
    const float* __restrict__ gam, const float* __restrict__ bet,
    float* __restrict__ of32, uint16_t* __restrict__ ob16) {
  int row = blockIdx.x, t = threadIdx.x;
  int w = t >> 6, l = t & 63;
  float v0, v1, v2, v3;
  if (XBF) {
    uint2 u = ((const uint2*)((const uint16_t*)xr + (size_t)row * 1024))[t];
    v0 = __uint_as_float((u.x & 0xffffu) << 16);
    v1 = __uint_as_float(u.x & 0xffff0000u);
    v2 = __uint_as_float((u.y & 0xffffu) << 16);
    v3 = __uint_as_float(u.y & 0xffff0000u);
  } else {
    float4 xv = ((const float4*)((const float*)xr + (size_t)row * 1024))[t];
    v0 = xv.x; v1 = xv.y; v2 = xv.z; v3 = xv.w;
  }
#pragma unroll
  for (int p = 0; p < NPART; p++) {
    uint2 u = ((const uint2*)(parts + (size_t)p * 4096 * 1024 +
                              (size_t)row * 1024))[t];
    v0 += __uint_as_float((u.x & 0xffffu) << 16);
    v1 += __uint_as_float(u.x & 0xffff0000u);
    v2 += __uint_as_float((u.y & 0xffffu) << 16);
    v3 += __uint_as_float(u.y & 0xffff0000u);
  }
  float s = v0 + v1 + v2 + v3;
  float sq = v0 * v0 + v1 * v1 + v2 * v2 + v3 * v3;
#pragma unroll
  for (int d = 1; d < 64; d <<= 1) {
    s += __shfl_xor(s, d);
    sq += __shfl_xor(sq, d);
  }
  __shared__ float red[8];
  if (l == 0) { red[w] = s; red[4 + w] = sq; }
  __syncthreads();
  s = red[0] + red[1] + red[2] + red[3];
  sq = red[4] + red[5] + red[6] + red[7];
  float mean = s * (1.f / 1024.f);
  float var = sq * (1.f / 1024.f) - mean * mean;
  float rstd = rsqrtf(var + 1e-5f);
  float4 gv = ((const float4*)gam)[t];
  float4 bv = ((const float4*)bet)[t];
  float y0 = (v0 - mean) * rstd * gv.x + bv.x;
  float y1 = (v1 - mean) * rstd * gv.y + bv.y;
  float y2 = (v2 - mean) * rstd * gv.z + bv.z;
  float y3 = (v3 - mean) * rstd * gv.w + bv.w;
  if (WF32) {
    float4 yv; yv.x = y0; yv.y = y1; yv.z = y2; yv.w = y3;
    ((float4*)(of32 + (size_t)row * 1024))[t] = yv;
  }
  if (WB16) {
    uint2 r;
    r.x = pkbf2(y0, y1);
    r.y = pkbf2(y2, y3);
    ((uint2*)(ob16 + (size_t)row * 1024))[t] = r;
  }
}

// ---------------------------------------------------------------- workspace map
static constexpr size_t OFF_XB    = 0;                          // 8 MB x_bf16 (live thru LN1)
static constexpr size_t OFF_WQKVT = (size_t)8 << 20;            // 6 MB [3072][1024]
static constexpr size_t OFF_WOT   = (size_t)14 << 20;           // 2 MB [1024][1024]
static constexpr size_t OFF_W1T   = (size_t)16 << 20;           // 8 MB [4096][1024]
static constexpr size_t OFF_W2T   = (size_t)24 << 20;           // 8 MB [1024][4096]
static constexpr size_t OFF_BIAS  = (size_t)32 << 20;           // 12 KB f32 (pad 64K)
static constexpr size_t OFF_QKV   = OFF_BIAS + ((size_t)64 << 10);  // 24 MB; +VT reused: H (32MB)
static constexpr size_t OFF_VT    = OFF_QKV + ((size_t)24 << 20);   // 8 MB [32][64][2048]
static constexpr size_t OFF_PROJ  = OFF_VT + ((size_t)8 << 20);     // 32 MB: 4x bf16 partials
static constexpr size_t OFF_LN1B  = OFF_PROJ + ((size_t)32 << 20);  // 8 MB bf16 trunk
static constexpr size_t OFF_ATTN  = OFF_LN1B + ((size_t)8 << 20);   // 8 MB attn out
// total ~120 MB

extern "C" void kernel_launch(void* const* d_in, const int* in_sizes, int n_in,
                              void* d_out, int out_size, void* d_ws, size_t ws_size,
                              hipStream_t stream) {
  const float* x   = (const float*)d_in[0];
  const float* Wq  = (const float*)d_in[1];
  const float* bq  = (const float*)d_in[2];
  const float* Wk  = (const float*)d_in[3];
  const float* bk  = (const float*)d_in[4];
  const float* Wv  = (const float*)d_in[5];
  const float* bv  = (const float*)d_in[6];
  const float* Wo  = (const float*)d_in[7];
  const float* bo  = (const float*)d_in[8];
  const float* W1  = (const float*)d_in[9];
  const float* b1  = (const float*)d_in[10];
  const float* W2  = (const float*)d_in[11];
  const float* b2  = (const float*)d_in[12];
  const float* g1  = (const float*)d_in[13];
  const float* be1 = (const float*)d_in[14];
  const float* g2  = (const float*)d_in[15];
  const float* be2 = (const float*)d_in[16];
  float* out = (float*)d_out;
  uint8_t* ws = (uint8_t*)d_ws;

  uint16_t* xb    = (uint16_t*)(ws + OFF_XB);
  uint16_t* wqkt  = (uint16_t*)(ws + OFF_WQKVT);
  uint16_t* wot   = (uint16_t*)(ws + OFF_WOT);
  uint16_t* w1t   = (uint16_t*)(ws + OFF_W1T);
  uint16_t* w2t   = (uint16_t*)(ws + OFF_W2T);
  float*    bqkv  = (float*)(ws + OFF_BIAS);
  uint16_t* qkvb  = (uint16_t*)(ws + OFF_QKV);
  uint16_t* vt    = (uint16_t*)(ws + OFF_VT);
  uint16_t* proj  = (uint16_t*)(ws + OFF_PROJ);   // up to 4x contiguous partials
  uint16_t* ln1b  = (uint16_t*)(ws + OFF_LN1B);
  uint16_t* attnb = (uint16_t*)(ws + OFF_ATTN);
  uint16_t* hbuf  = (uint16_t*)(ws + OFF_QKV);  // alias: qkv+vt dead after attention

  // 1. merged prep: cast x, all weight transposes, bias concat (one dispatch)
  prep_all<<<16396, 256, 0, stream>>>(x, xb, Wq, Wk, Wv, wqkt, Wo, wot,
                                      W1, w1t, W2, w2t, bq, bk, bv, bqkv);
  // 2. fused QKV projection; V columns written directly transposed to vt
  gemm_bt<1, 1, 32, 1><<<768, 256, 0, stream>>>(xb, wqkt, bqkv, qkvb, vt,
                                                4096, 3072, 1024, 24);
  // 3. fused attention (512 blocks, single-buffer KVBLK=128)
  attn_fused<<<512, 256, 0, stream>>>(qkvb, vt, attnb);
  // 4. output projection: 128x128 split-K x2, BK=64 (512 blocks, 2/CU)
  gemm_bt<1, 2, 64, 0><<<512, 256, 0, stream>>>(attnb, wot, bo, proj, nullptr,
                                                4096, 1024, 1024, 8);
  // 5. LN1(xb + p0 + p1) -> bf16 trunk only
  ln_res<1, 0, 1, 2><<<4096, 256, 0, stream>>>(xb, proj, g1, be1,
                                               nullptr, ln1b);
  // 6. MLP1 + relu -> bf16, 256x256 phase-split (256 blocks, 1/CU, nt=16)
  gemm256<2, 1><<<256, 512, 0, stream>>>(ln1b, w1t, b1, hbuf,
                                         4096, 4096, 1024, 16);
  // 7. MLP2: 256x256 phase-split, split-K x4 (256 blocks, nt=16)
  gemm256<1, 4><<<256, 512, 0, stream>>>(hbuf, w2t, b2, proj,
                                         4096, 1024, 4096, 4);
  // 8. LN2(ln1b + p0..p3) -> d_out fp32
  ln_res<1, 1, 0, 4><<<4096, 256, 0, stream>>>(ln1b, proj, g2, be2,
                                               out, nullptr);
}